// Round 6
// baseline (435.852 us; speedup 1.0000x reference)
//
#include <hip/hip_runtime.h>
#include <math.h>

#define N_HEADS 8
#define HEAD_DIM 16
#define HID 128
// qkv row: 256B q (bf16) + 16 x [8B k fp8 | 8B v fp8] = 512B
#define QKV_ROWB 512

typedef unsigned short ushort_t;
typedef __attribute__((ext_vector_type(8))) short short8;
typedef __attribute__((ext_vector_type(4))) float floatx4;
typedef __attribute__((ext_vector_type(2))) float f32x2;

#define KV_SCALE 64.0f
#define KV_INV_SCALE 0.015625f

__device__ __forceinline__ ushort_t f2bf(float f) {
    unsigned u = __float_as_uint(f);
    unsigned r = (u + 0x7FFFu + ((u >> 16) & 1u)) >> 16;
    return (ushort_t)r;
}
__device__ __forceinline__ float bf2f(ushort_t u) {
    return __uint_as_float(((unsigned)u) << 16);
}

// fast exact-GELU: erf via Abramowitz-Stegun 7.1.26 (|err| <= 1.5e-7)
__device__ __forceinline__ float gelu_f(float x) {
    float z = fabsf(x) * 0.70710678118654752f;
    float t = 1.0f / (1.0f + 0.3275911f * z);
    float y = t * (0.254829592f + t * (-0.284496736f + t * (1.421413741f
            + t * (-1.453152027f + t * 1.061405429f))));
    float e = 1.0f - y * __expf(-z * z);
    e = copysignf(e, x);
    return 0.5f * x * (1.0f + e);
}

// ---- prep kernel: cvt x, cvt 6 weights, pack qkv bias, count dst degrees ----
__global__ __launch_bounds__(256)
void prep_kernel(const float* __restrict__ x,
                 const float* __restrict__ Wq, const float* __restrict__ Wk,
                 const float* __restrict__ Wv, const float* __restrict__ Wo,
                 const float* __restrict__ W1, const float* __restrict__ W2,
                 const float* __restrict__ bq, const float* __restrict__ bk,
                 const float* __restrict__ bv,
                 const int* __restrict__ dst, int* __restrict__ cnt, int E,
                 ushort_t* __restrict__ xb, ushort_t* __restrict__ wts,
                 float* __restrict__ bqkv, int xpairs)
{
    int i = blockIdx.x * 256 + threadIdx.x;
    if (i < xpairs) {
        float2 v = ((const float2*)x)[i];
        xb[i * 2]     = f2bf(v.x);
        xb[i * 2 + 1] = f2bf(v.y);
        return;
    }
    int j = i - xpairs;
    if (j < 98304) {
        const float* s; int off;
        if (j < 32768) {
            if (j < 8192)       { s = Wq; off = j; }
            else if (j < 16384) { s = Wk; off = j - 8192; }
            else if (j < 24576) { s = Wv; off = j - 16384; }
            else                { s = Wo; off = j - 24576; }
        } else if (j < 65536)   { s = W1; off = j - 32768; }
        else                    { s = W2; off = j - 65536; }
        float2 v = ((const float2*)s)[off];
        wts[j * 2]     = f2bf(v.x);
        wts[j * 2 + 1] = f2bf(v.y);
        return;
    }
    int b = j - 98304;
    if (b < 384) {
        bqkv[b] = (b < 128) ? bq[b] : (b < 256) ? bk[b - 128] : bv[b - 256];
        return;
    }
    int e = b - 384;
    if (e < E) atomicAdd(&cnt[dst[e]], 1);
}

// ---------------- 1-wave register GEMM: 16 rows x 128 cols per block ---------
// No inter-wave coupling: A/B fragments loaded straight from global (16B/lane,
// coalesced; W is L2/L3-hot), 8 MFMAs per 32-k chunk, wave-internal epilogue.
// OUTF: 0 = bf16 out, 1 = f32 out (direct), 3 = merged QKV (y0 q bf16 into
// 512B rows, y1/y2 k/v fp8 x64 into interleaved chunks).
template<int K, int ACT, int LN, int OUTF>
__global__ __launch_bounds__(64)
void gemm1w(const ushort_t* __restrict__ A,
            const ushort_t* __restrict__ W,
            const float* __restrict__ bias,
            float* __restrict__ outf, ushort_t* __restrict__ outb, int ostride,
            const float* __restrict__ resf, const ushort_t* __restrict__ resb,
            const float* __restrict__ g, const float* __restrict__ be)
{
    __shared__ __align__(16) ushort_t B16[16 * 136];
    const int lane = threadIdx.x;
    const int l15 = lane & 15, l4 = lane >> 4;
    const int gm0 = blockIdx.x * 16;
    const int o0  = blockIdx.y * 128;

    floatx4 acc[8];
#pragma unroll
    for (int j = 0; j < 8; ++j) acc[j] = (floatx4)(0.f);

    const ushort_t* ap = A + (size_t)(gm0 + l15) * K + l4 * 8;
    const ushort_t* wp = W + (size_t)(o0 + l15) * K + l4 * 8;

    for (int kst = 0; kst < K / 32; ++kst) {
        short8 av = *(const short8*)(ap + kst * 32);
        short8 bv[8];
#pragma unroll
        for (int j = 0; j < 8; ++j)
            bv[j] = *(const short8*)(wp + (size_t)j * 16 * K + kst * 32);
#pragma unroll
        for (int j = 0; j < 8; ++j)
            acc[j] = __builtin_amdgcn_mfma_f32_16x16x32_bf16(av, bv[j], acc[j], 0, 0, 0);
    }

    if (LN) {
        // bias + residual, then per-row stats via 16-lane butterfly (o0 == 0)
        float gv[8], bev[8];
#pragma unroll
        for (int j = 0; j < 8; ++j) {
            int oc = j * 16 + l15;
            float bj = bias[oc];
            gv[j] = g[oc]; bev[j] = be[oc];
#pragma unroll
            for (int r = 0; r < 4; ++r) {
                int row = gm0 + l4 * 4 + r;
                float rv = resf ? resf[(size_t)row * HID + oc]
                                : bf2f(resb[(size_t)row * HID + oc]);
                acc[j][r] += bj + rv;
            }
        }
#pragma unroll
        for (int r = 0; r < 4; ++r) {
            float s1 = 0.f, s2 = 0.f;
#pragma unroll
            for (int j = 0; j < 8; ++j) {
                s1 += acc[j][r];
                s2 += acc[j][r] * acc[j][r];
            }
            s1 += __shfl_xor(s1, 1); s1 += __shfl_xor(s1, 2);
            s1 += __shfl_xor(s1, 4); s1 += __shfl_xor(s1, 8);
            s2 += __shfl_xor(s2, 1); s2 += __shfl_xor(s2, 2);
            s2 += __shfl_xor(s2, 4); s2 += __shfl_xor(s2, 8);
            float mu = s1 * (1.f / 128.f);
            float var = s2 * (1.f / 128.f) - mu * mu;
            float rstd = rsqrtf(var + 1e-5f);
#pragma unroll
            for (int j = 0; j < 8; ++j)
                acc[j][r] = (acc[j][r] - mu) * rstd * gv[j] + bev[j];
        }
    }

    if (OUTF == 1) {            // direct f32 store (final output)
#pragma unroll
        for (int j = 0; j < 8; ++j)
#pragma unroll
            for (int r = 0; r < 4; ++r)
                outf[(size_t)(gm0 + l4 * 4 + r) * HID + j * 16 + l15] = acc[j][r];
        return;
    }

    // ---- bf16 / fp8-kv epilogue via wave-internal LDS transpose ----
    const bool kvout = (OUTF == 3) && (blockIdx.y > 0);
#pragma unroll
    for (int j = 0; j < 8; ++j) {
        float bj = LN ? 0.f : bias[o0 + j * 16 + l15];
#pragma unroll
        for (int r = 0; r < 4; ++r) {
            float v = acc[j][r] + bj;
            if (ACT) v = gelu_f(v);
            if (kvout) v *= KV_SCALE;
            B16[(l4 * 4 + r) * 136 + j * 16 + l15] = f2bf(v);
        }
    }
    __syncthreads();            // 1-wave block: compiles to a waitcnt, ~free

    if (kvout) {
        const int koff = (blockIdx.y - 1) * 8;
#pragma unroll
        for (int c = 0; c < 4; ++c) {
            int ch = l4 * 4 + c;
            short8 s = *(const short8*)&B16[l15 * 136 + ch * 8];
            unsigned u0 = 0, u1 = 0;
            u0 = __builtin_amdgcn_cvt_pk_fp8_f32(
                     bf2f((ushort_t)s[0]), bf2f((ushort_t)s[1]), u0, false);
            u0 = __builtin_amdgcn_cvt_pk_fp8_f32(
                     bf2f((ushort_t)s[2]), bf2f((ushort_t)s[3]), u0, true);
            u1 = __builtin_amdgcn_cvt_pk_fp8_f32(
                     bf2f((ushort_t)s[4]), bf2f((ushort_t)s[5]), u1, false);
            u1 = __builtin_amdgcn_cvt_pk_fp8_f32(
                     bf2f((ushort_t)s[6]), bf2f((ushort_t)s[7]), u1, true);
            uint2 o; o.x = u0; o.y = u1;
            *(uint2*)((char*)outb + (size_t)(gm0 + l15) * QKV_ROWB
                      + 256 + ch * 16 + koff) = o;
        }
    } else {
        const int oo = (OUTF == 3) ? 0 : o0;
#pragma unroll
        for (int c = 0; c < 4; ++c) {
            int ch = l4 * 4 + c;
            *(short8*)&outb[(size_t)(gm0 + l15) * ostride + oo + ch * 8] =
                *(const short8*)&B16[l15 * 136 + ch * 8];
        }
    }
}

// ---------------- counting-sort scan chain ----------------------------------
__global__ __launch_bounds__(256)
void scan1_kernel(const int* __restrict__ cnt, int* __restrict__ parts, int N)
{
    __shared__ int sd[256];
    int t = threadIdx.x;
    int base = blockIdx.x * 1024 + t * 4;
    int s = 0;
#pragma unroll
    for (int j = 0; j < 4; ++j) if (base + j < N) s += cnt[base + j];
    sd[t] = s; __syncthreads();
    for (int off = 128; off; off >>= 1) {
        if (t < off) sd[t] += sd[t + off];
        __syncthreads();
    }
    if (t == 0) parts[blockIdx.x] = sd[0];
}

__global__ __launch_bounds__(256)
void scan2_kernel(const int* __restrict__ parts, int* __restrict__ poff, int nb)
{
    __shared__ int sd[256];
    int t = threadIdx.x;
    int v = (t < nb) ? parts[t] : 0;
    sd[t] = v; __syncthreads();
    for (int off = 1; off < 256; off <<= 1) {
        int u = (t >= off) ? sd[t - off] : 0;
        __syncthreads();
        sd[t] += u;
        __syncthreads();
    }
    if (t < nb) poff[t] = sd[t] - v;   // exclusive
}

__global__ __launch_bounds__(256)
void scan3_kernel(const int* __restrict__ cnt, const int* __restrict__ poff,
                  int* __restrict__ rp, int N)
{
    __shared__ int sd[256];
    int t = threadIdx.x;
    int base = blockIdx.x * 1024 + t * 4;
    int v0 = (base + 0 < N) ? cnt[base + 0] : 0;
    int v1 = (base + 1 < N) ? cnt[base + 1] : 0;
    int v2 = (base + 2 < N) ? cnt[base + 2] : 0;
    int v3 = (base + 3 < N) ? cnt[base + 3] : 0;
    int s = v0 + v1 + v2 + v3;
    sd[t] = s; __syncthreads();
    for (int off = 1; off < 256; off <<= 1) {
        int u = (t >= off) ? sd[t - off] : 0;
        __syncthreads();
        sd[t] += u;
        __syncthreads();
    }
    int o = poff[blockIdx.x] + sd[t] - s;
    if (base + 0 < N) rp[base + 0] = o;
    if (base + 1 < N) rp[base + 1] = o + v0;
    if (base + 2 < N) rp[base + 2] = o + v0 + v1;
    if (base + 3 < N) rp[base + 3] = o + v0 + v1 + v2;
}

// cohort scatter: blockIdx.x & 7 keys the XCD; each cohort owns 1/8 of nodes.
__global__ __launch_bounds__(256)
void scatter_kernel(const int* __restrict__ src, const int* __restrict__ dst,
                    int* __restrict__ rp, int* __restrict__ ssrc, int E, int N)
{
    int coh = blockIdx.x & 7;
    int bc  = blockIdx.x >> 3;
    int rr  = (N + 7) >> 3;
    int nlo = coh * rr;
    int nhi = nlo + rr; if (nhi > N) nhi = N;
    int stride = (gridDim.x >> 3) * 256;
    for (int e = bc * 256 + threadIdx.x; e < E; e += stride) {
        int d = dst[e];
        if (d >= nlo && d < nhi) {
            int pos = atomicAdd(&rp[d], 1);
            ssrc[pos] = src[e];
        }
    }
}

// ---------------- fused attention: 4 edges per wave-step ---------------------
__global__ __launch_bounds__(256)
void attn_fused_kernel(const ushort_t* __restrict__ qkvb, const int* __restrict__ rp,
                       const int* __restrict__ ssrc, ushort_t* __restrict__ aggb, int N)
{
    int wave = threadIdx.x >> 6, lane = threadIdx.x & 63;
    int n = blockIdx.x * 4 + wave;
    if (n >= N) return;
    int grp = lane >> 4;            // 0..3 edge slot
    int cb  = (lane & 15) * 16;     // byte offset of this lane's 16B chunk
    const char* base = (const char*)qkvb;

    short8 qv = *(const short8*)(base + n * QKV_ROWB + cb);
    float q[8];
#pragma unroll
    for (int j = 0; j < 8; ++j) q[j] = bf2f((ushort_t)qv[j]) * (0.25f / KV_SCALE);

    int r0 = n ? rp[n - 1] : 0;
    int r1 = rp[n];
    float acc[8] = {0.f, 0.f, 0.f, 0.f, 0.f, 0.f, 0.f, 0.f};
    float l = 0.f;

    int r = r0;
    for (; r + 8 <= r1; r += 8) {
        int s0 = ssrc[r + grp];
        int s1 = ssrc[r + 4 + grp];
        uint4 kv0 = *(const uint4*)(base + s0 * QKV_ROWB + 256 + cb);
        uint4 kv1 = *(const uint4*)(base + s1 * QKV_ROWB + 256 + cb);

        f32x2 a0 = __builtin_amdgcn_cvt_pk_f32_fp8(kv0.x, false);
        f32x2 a1 = __builtin_amdgcn_cvt_pk_f32_fp8(kv0.x, true);
        f32x2 a2 = __builtin_amdgcn_cvt_pk_f32_fp8(kv0.y, false);
        f32x2 a3 = __builtin_amdgcn_cvt_pk_f32_fp8(kv0.y, true);
        f32x2 b0 = __builtin_amdgcn_cvt_pk_f32_fp8(kv1.x, false);
        f32x2 b1 = __builtin_amdgcn_cvt_pk_f32_fp8(kv1.x, true);
        f32x2 b2 = __builtin_amdgcn_cvt_pk_f32_fp8(kv1.y, false);
        f32x2 b3 = __builtin_amdgcn_cvt_pk_f32_fp8(kv1.y, true);

        float p0 = 0.f, p1 = 0.f;
        p0 = fmaf(q[0], a0.x, p0); p0 = fmaf(q[1], a0.y, p0);
        p0 = fmaf(q[2], a1.x, p0); p0 = fmaf(q[3], a1.y, p0);
        p0 = fmaf(q[4], a2.x, p0); p0 = fmaf(q[5], a2.y, p0);
        p0 = fmaf(q[6], a3.x, p0); p0 = fmaf(q[7], a3.y, p0);
        p1 = fmaf(q[0], b0.x, p1); p1 = fmaf(q[1], b0.y, p1);
        p1 = fmaf(q[2], b1.x, p1); p1 = fmaf(q[3], b1.y, p1);
        p1 = fmaf(q[4], b2.x, p1); p1 = fmaf(q[5], b2.y, p1);
        p1 = fmaf(q[6], b3.x, p1); p1 = fmaf(q[7], b3.y, p1);

        p0 += __shfl_xor(p0, 1);
        p1 += __shfl_xor(p1, 1);
        float e0 = __expf(p0), e1 = __expf(p1);
        l += e0 + e1;

        f32x2 v0 = __builtin_amdgcn_cvt_pk_f32_fp8(kv0.z, false);
        f32x2 v1 = __builtin_amdgcn_cvt_pk_f32_fp8(kv0.z, true);
        f32x2 v2 = __builtin_amdgcn_cvt_pk_f32_fp8(kv0.w, false);
        f32x2 v3 = __builtin_amdgcn_cvt_pk_f32_fp8(kv0.w, true);
        f32x2 w0 = __builtin_amdgcn_cvt_pk_f32_fp8(kv1.z, false);
        f32x2 w1 = __builtin_amdgcn_cvt_pk_f32_fp8(kv1.z, true);
        f32x2 w2 = __builtin_amdgcn_cvt_pk_f32_fp8(kv1.w, false);
        f32x2 w3 = __builtin_amdgcn_cvt_pk_f32_fp8(kv1.w, true);

        acc[0] = fmaf(e0, v0.x, acc[0]); acc[1] = fmaf(e0, v0.y, acc[1]);
        acc[2] = fmaf(e0, v1.x, acc[2]); acc[3] = fmaf(e0, v1.y, acc[3]);
        acc[4] = fmaf(e0, v2.x, acc[4]); acc[5] = fmaf(e0, v2.y, acc[5]);
        acc[6] = fmaf(e0, v3.x, acc[6]); acc[7] = fmaf(e0, v3.y, acc[7]);
        acc[0] = fmaf(e1, w0.x, acc[0]); acc[1] = fmaf(e1, w0.y, acc[1]);
        acc[2] = fmaf(e1, w1.x, acc[2]); acc[3] = fmaf(e1, w1.y, acc[3]);
        acc[4] = fmaf(e1, w2.x, acc[4]); acc[5] = fmaf(e1, w2.y, acc[5]);
        acc[6] = fmaf(e1, w3.x, acc[6]); acc[7] = fmaf(e1, w3.y, acc[7]);
    }
    for (; r < r1; r += 4) {
        int e = r + grp;
        int s = ssrc[(e < r1) ? e : r0];
        uint4 kv = *(const uint4*)(base + s * QKV_ROWB + 256 + cb);
        f32x2 a0 = __builtin_amdgcn_cvt_pk_f32_fp8(kv.x, false);
        f32x2 a1 = __builtin_amdgcn_cvt_pk_f32_fp8(kv.x, true);
        f32x2 a2 = __builtin_amdgcn_cvt_pk_f32_fp8(kv.y, false);
        f32x2 a3 = __builtin_amdgcn_cvt_pk_f32_fp8(kv.y, true);
        float p = 0.f;
        p = fmaf(q[0], a0.x, p); p = fmaf(q[1], a0.y, p);
        p = fmaf(q[2], a1.x, p); p = fmaf(q[3], a1.y, p);
        p = fmaf(q[4], a2.x, p); p = fmaf(q[5], a2.y, p);
        p = fmaf(q[6], a3.x, p); p = fmaf(q[7], a3.y, p);
        p += __shfl_xor(p, 1);
        float ea = (e < r1) ? __expf(p) : 0.f;
        l += ea;
        f32x2 v0 = __builtin_amdgcn_cvt_pk_f32_fp8(kv.z, false);
        f32x2 v1 = __builtin_amdgcn_cvt_pk_f32_fp8(kv.z, true);
        f32x2 v2 = __builtin_amdgcn_cvt_pk_f32_fp8(kv.w, false);
        f32x2 v3 = __builtin_amdgcn_cvt_pk_f32_fp8(kv.w, true);
        acc[0] = fmaf(ea, v0.x, acc[0]); acc[1] = fmaf(ea, v0.y, acc[1]);
        acc[2] = fmaf(ea, v1.x, acc[2]); acc[3] = fmaf(ea, v1.y, acc[3]);
        acc[4] = fmaf(ea, v2.x, acc[4]); acc[5] = fmaf(ea, v2.y, acc[5]);
        acc[6] = fmaf(ea, v3.x, acc[6]); acc[7] = fmaf(ea, v3.y, acc[7]);
    }

#pragma unroll
    for (int j = 0; j < 8; ++j) {
        acc[j] += __shfl_xor(acc[j], 16);
        acc[j] += __shfl_xor(acc[j], 32);
    }
    l += __shfl_xor(l, 16);
    l += __shfl_xor(l, 32);
    float inv = KV_INV_SCALE / (l + 1e-16f);
    if (grp == 0) {
        short8 o;
#pragma unroll
        for (int j = 0; j < 8; ++j) o[j] = (short)f2bf(acc[j] * inv);
        *(short8*)((char*)aggb + n * 256 + cb) = o;
    }
}

// ============================================================================
extern "C" void kernel_launch(void* const* d_in, const int* in_sizes, int n_in,
                              void* d_out, int out_size, void* d_ws, size_t ws_size,
                              hipStream_t stream)
{
    const float* x  = (const float*)d_in[0];
    const int*   ei = (const int*)d_in[1];
    const float* Wq = (const float*)d_in[2];
    const float* bq = (const float*)d_in[3];
    const float* Wk = (const float*)d_in[4];
    const float* bk = (const float*)d_in[5];
    const float* Wv = (const float*)d_in[6];
    const float* bv = (const float*)d_in[7];
    const float* Wo = (const float*)d_in[8];
    const float* bo = (const float*)d_in[9];
    const float* W1 = (const float*)d_in[10];
    const float* b1 = (const float*)d_in[11];
    const float* W2 = (const float*)d_in[12];
    const float* b2 = (const float*)d_in[13];
    const float* g1 = (const float*)d_in[14];
    const float* be1= (const float*)d_in[15];
    const float* g2 = (const float*)d_in[16];
    const float* be2= (const float*)d_in[17];
    float* out = (float*)d_out;

    const int N = in_sizes[0] / HID;      // 50000
    const int E = in_sizes[1] / 2;        // 800000
    const int* srcp = ei;
    const int* dstp = ei + E;

    const size_t NH = (size_t)N * HID;    // 6.4M
    float* wsf = (float*)d_ws;

    // ---- workspace layout (f32 units) ----
    ushort_t* xb   = (ushort_t*)wsf;                  // [0, 0.5NH)  dies after QKV
    ushort_t* qkvb = (ushort_t*)(wsf + NH / 2);       // [0.5, 1.5)  dies after attn
    ushort_t* aggb = (ushort_t*)(wsf + 2 * NH);       // [2.0, 2.5)  dies after Wo
    ushort_t* hb   = (ushort_t*)wsf;                  // [0, 0.5)    overlays dead xb
    ushort_t* ffb  = (ushort_t*)(wsf + NH / 2);       // [0.5, 2.5)  overlays dead qkvb/aggb

    ushort_t* wts  = (ushort_t*)(wsf + 2 * NH + NH / 2);  // 196608 ushort
    float*    bqkv = (float*)(wts + 196608);              // 384 f32
    int*      rp   = (int*)(bqkv + 384);                  // N+1
    int*      cnt  = rp + (N + 1);                        // N
    int*      poff = cnt + N;                             // 256
    int*      parts= poff + 256;                          // 256
    int*      ssrc = parts + 256;                         // E

    // ---- prep (+fused degree count; cnt zeroed first) ----
    hipMemsetAsync(cnt, 0, N * sizeof(int), stream);
    const int xpairs = (int)(NH / 2);
    const int ptot   = xpairs + 98304 + 384 + E;
    prep_kernel<<<(ptot + 255) / 256, 256, 0, stream>>>(
        x, Wq, Wk, Wv, Wo, W1, W2, bq, bk, bv, dstp, cnt, E,
        xb, wts, bqkv, xpairs);

    // ---- counting sort of edges by dst ----
    const int nb = (N + 1023) / 1024;   // 49
    scan1_kernel<<<nb, 256, 0, stream>>>(cnt, parts, N);
    scan2_kernel<<<1, 256, 0, stream>>>(parts, poff, nb);
    scan3_kernel<<<nb, 256, 0, stream>>>(cnt, poff, rp, N);
    scatter_kernel<<<2048, 256, 0, stream>>>(srcp, dstp, rp, ssrc, E, N);

    const int gx16 = (N + 15) / 16;     // 3125 (exact: 50000 = 16*3125)

    // ---- merged QKV (1-wave blocks): y=0 -> q bf16, y=1/2 -> k/v fp8 ----
    gemm1w<128, 0, 0, 3><<<dim3(gx16, 3), 64, 0, stream>>>(
        xb, wts, bqkv, nullptr, qkvb, 256,
        nullptr, nullptr, nullptr, nullptr);

    // ---- fused attention ----
    attn_fused_kernel<<<(N + 3) / 4, 256, 0, stream>>>(qkvb, rp, ssrc, aggb, N);

    // ---- Wo + residual(x) + LN1 -> hb (bf16) ----
    gemm1w<128, 0, 1, 0><<<dim3(gx16, 1), 64, 0, stream>>>(
        aggb, wts + 49152, bo, nullptr, hb, HID,
        x, nullptr, g1, be1);

    // ---- FF1 + GELU -> ffb (bf16), 4 col-chunks ----
    gemm1w<128, 1, 0, 0><<<dim3(gx16, 4), 64, 0, stream>>>(
        hb, wts + 65536, b1, nullptr, ffb, 512,
        nullptr, nullptr, nullptr, nullptr);

    // ---- FF2 + residual(hb) + LN2 -> out (f32) ----
    gemm1w<512, 0, 1, 1><<<dim3(gx16, 1), 64, 0, stream>>>(
        ffb, wts + 131072, b2, out, nullptr, HID,
        nullptr, hb, g2, be2);
}

// Round 7
// 323.936 us; speedup vs baseline: 1.3455x; 1.3455x over previous
//
#include <hip/hip_runtime.h>
#include <math.h>

#define N_HEADS 8
#define HEAD_DIM 16
#define HID 128
// qkv row: 256B q (bf16) + 16 x [8B k fp8 | 8B v fp8] = 512B
#define QKV_ROWB 512

typedef unsigned short ushort_t;
typedef __attribute__((ext_vector_type(8))) short short8;
typedef __attribute__((ext_vector_type(4))) float floatx4;
typedef __attribute__((ext_vector_type(2))) float f32x2;

#define KV_SCALE 64.0f
#define KV_INV_SCALE 0.015625f

// FF fp8 scales: W2 x 2^16, a1 x 2^9
#define W2_SCALE 65536.0f
#define A1_SCALE 512.0f
#define FF2_DESCALE (1.0f / 33554432.0f)   // 1/(512*65536)

__device__ __forceinline__ ushort_t f2bf(float f) {
    unsigned u = __float_as_uint(f);
    unsigned r = (u + 0x7FFFu + ((u >> 16) & 1u)) >> 16;
    return (ushort_t)r;
}
__device__ __forceinline__ float bf2f(ushort_t u) {
    return __uint_as_float(((unsigned)u) << 16);
}

__device__ __forceinline__ void gld_lds16(const void* g, void* l) {
    __builtin_amdgcn_global_load_lds(
        (const __attribute__((address_space(1))) void*)g,
        (__attribute__((address_space(3))) void*)l, 16, 0, 0);
}

// fast exact-GELU: erf via Abramowitz-Stegun 7.1.26 (|err| <= 1.5e-7)
__device__ __forceinline__ float gelu_f(float x) {
    float z = fabsf(x) * 0.70710678118654752f;
    float t = 1.0f / (1.0f + 0.3275911f * z);
    float y = t * (0.254829592f + t * (-0.284496736f + t * (1.421413741f
            + t * (-1.453152027f + t * 1.061405429f))));
    float e = 1.0f - y * __expf(-z * z);
    e = copysignf(e, x);
    return 0.5f * x * (1.0f + e);
}

// ---- prep: cvt x, Wq..Wo bf16, qkv bias, W1-frag bf16, W2-frag fp8, degrees -
// frag layout (16x16x32 MFMA B/A): [tile16][kst][lane][8], elem =
// Wrow(tile16*16 + (lane&15)), k(kst*32 + (lane>>4)*8 + e) — one wave frag
// load is a single coalesced 512B/1KB segment.
__global__ __launch_bounds__(256)
void prep_kernel(const float* __restrict__ x,
                 const float* __restrict__ Wq, const float* __restrict__ Wk,
                 const float* __restrict__ Wv, const float* __restrict__ Wo,
                 const float* __restrict__ W1, const float* __restrict__ W2,
                 const float* __restrict__ bq, const float* __restrict__ bk,
                 const float* __restrict__ bv,
                 const int* __restrict__ dst, int* __restrict__ cnt, int E,
                 ushort_t* __restrict__ xb, ushort_t* __restrict__ wts,
                 float* __restrict__ bqkv,
                 ushort_t* __restrict__ w1frag,
                 unsigned char* __restrict__ w2frag8, int xpairs)
{
    int i = blockIdx.x * 256 + threadIdx.x;
    if (i < xpairs) {
        float2 v = ((const float2*)x)[i];
        xb[i * 2]     = f2bf(v.x);
        xb[i * 2 + 1] = f2bf(v.y);
        return;
    }
    int j = i - xpairs;
    if (j < 32768) {                        // Wq,Wk,Wv,Wo -> bf16 (row-major)
        const float* s; int off;
        if (j < 8192)       { s = Wq; off = j; }
        else if (j < 16384) { s = Wk; off = j - 8192; }
        else if (j < 24576) { s = Wv; off = j - 16384; }
        else                { s = Wo; off = j - 24576; }
        float2 v = ((const float2*)s)[off];
        wts[j * 2]     = f2bf(v.x);
        wts[j * 2 + 1] = f2bf(v.y);
        return;
    }
    int b = j - 32768;
    if (b < 384) {
        bqkv[b] = (b < 128) ? bq[b] : (b < 256) ? bk[b - 128] : bv[b - 256];
        return;
    }
    int c = b - 384;
    if (c < 8192) {                         // W1-frag bf16: [32 t16][4 kst][64][8]
        int lane = c & 63, tk = c >> 6;
        int t16 = tk >> 2, kst = tk & 3;
        int row = t16 * 16 + (lane & 15);
        int kb  = kst * 32 + (lane >> 4) * 8;
        const float* s = W1 + (size_t)row * HID + kb;
        ushort_t* d = w1frag + (size_t)c * 8;
#pragma unroll
        for (int e = 0; e < 8; ++e) d[e] = f2bf(s[e]);
        return;
    }
    int c2 = c - 8192;
    if (c2 < 8192) {                        // W2-frag fp8 x2^16: [8 t16][16 kst][64][8]
        int lane = c2 & 63, tk = c2 >> 6;
        int t16 = tk >> 4, kst = tk & 15;
        int row = t16 * 16 + (lane & 15);
        int kb  = kst * 32 + (lane >> 4) * 8;
        const float* s = W2 + (size_t)row * 512 + kb;
        unsigned u0 = 0, u1 = 0;
        u0 = __builtin_amdgcn_cvt_pk_fp8_f32(s[0]*W2_SCALE, s[1]*W2_SCALE, u0, false);
        u0 = __builtin_amdgcn_cvt_pk_fp8_f32(s[2]*W2_SCALE, s[3]*W2_SCALE, u0, true);
        u1 = __builtin_amdgcn_cvt_pk_fp8_f32(s[4]*W2_SCALE, s[5]*W2_SCALE, u1, false);
        u1 = __builtin_amdgcn_cvt_pk_fp8_f32(s[6]*W2_SCALE, s[7]*W2_SCALE, u1, true);
        uint2 o; o.x = u0; o.y = u1;
        *(uint2*)(w2frag8 + (size_t)c2 * 8) = o;
        return;
    }
    int e = c2 - 8192;
    if (e < E) atomicAdd(&cnt[dst[e]], 1);
}

// ---------------- templated bf16 MFMA GEMM (MT=64, dbuf) ---------------------
// OUTF: 0 = bf16 out (LN also emits h-frag image via hfragp),
//       3 = merged QKV (y=0 q bf16 into 512B rows, y=1/2 k/v fp8 interleave).
template<int MT, int ACT, int LN, int OUTF>
__global__ __launch_bounds__(256)
void gemm_t(const ushort_t* __restrict__ A, int lda, int M,
            const ushort_t* __restrict__ W, int K,
            const float* __restrict__ bias,
            ushort_t* __restrict__ hfragp, ushort_t* __restrict__ outb, int ostride,
            const float* __restrict__ resf, const ushort_t* __restrict__ resb,
            const float* __restrict__ g, const float* __restrict__ be)
{
    constexpr int MI   = MT / 32;
    constexpr int HALF = MT * 64 + 128 * 64;
    constexpr int BNC  = MT * 136;
    constexpr int SB   = (2 * HALF > BNC) ? 2 * HALF : BNC;
    __shared__ __align__(16) ushort_t sbuf[SB];
    __shared__ float pS[LN ? MT : 1][2];
    __shared__ float pQ[LN ? MT : 1][2];

    const int tid  = threadIdx.x;
    const int wave = tid >> 6, lane = tid & 63;
    const int gm0 = blockIdx.x * MT;
    const int o0  = blockIdx.y * 128;
    const int mhalf = wave >> 1, ohalf = wave & 1;

    auto stage = [&](int kc, int h) {
        ushort_t* As = sbuf + h * HALF;
        ushort_t* Ws = As + MT * 64;
#pragma unroll
        for (int it = 0; it < 4; ++it) {          // W tile 128x64
            int s   = it * 256 + tid;
            int ln  = s & 63;
            int grp = s >> 6;
            int tile = grp >> 1, kst = grp & 1;
            int row = tile * 16 + (ln & 15);
            int kk  = kst * 32 + (ln >> 4) * 8;
            gld_lds16(&W[(size_t)(o0 + row) * K + kc + kk],
                      &Ws[(it * 256 + wave * 64) * 8]);
        }
#pragma unroll
        for (int it = 0; it < MT / 32; ++it) {    // A tile MTx64
            int s   = it * 256 + tid;
            int ln  = s & 63;
            int grp = s >> 6;
            int tile = grp >> 1, kst = grp & 1;
            int row = tile * 16 + (ln & 15);
            int kk  = kst * 32 + (ln >> 4) * 8;
            int ar = gm0 + row; if (ar >= M) ar = M - 1;
            gld_lds16(&A[(size_t)ar * lda + kc + kk],
                      &As[(it * 256 + wave * 64) * 8]);
        }
    };

    floatx4 acc[MI][4];
#pragma unroll
    for (int i = 0; i < MI; ++i)
#pragma unroll
        for (int j = 0; j < 4; ++j) acc[i][j] = (floatx4)(0.f);

    const int nk = K >> 6;
    stage(0, 0);
    __syncthreads();
    for (int t = 0; t < nk; ++t) {
        if (t + 1 < nk) stage((t + 1) * 64, (t + 1) & 1);
        const ushort_t* As = sbuf + (t & 1) * HALF;
        const ushort_t* Ws = As + MT * 64;
#pragma unroll
        for (int kst = 0; kst < 2; ++kst) {
            short8 af[MI], wf[4];
#pragma unroll
            for (int i = 0; i < MI; ++i) {
                int mt = mhalf * MI + i;
                af[i] = *(const short8*)&As[((mt * 2 + kst) * 64 + lane) * 8];
            }
#pragma unroll
            for (int j = 0; j < 4; ++j) {
                int ot = ohalf * 4 + j;
                wf[j] = *(const short8*)&Ws[((ot * 2 + kst) * 64 + lane) * 8];
            }
#pragma unroll
            for (int i = 0; i < MI; ++i)
#pragma unroll
                for (int j = 0; j < 4; ++j)
                    acc[i][j] = __builtin_amdgcn_mfma_f32_16x16x32_bf16(
                        af[i], wf[j], acc[i][j], 0, 0, 0);
        }
        __syncthreads();
    }

    // ---- epilogue ----
    ushort_t* B16 = sbuf;

    if (LN) {
#pragma unroll
        for (int j = 0; j < 4; ++j) {
            int oc = (ohalf * 4 + j) * 16 + (lane & 15);
            float bj = bias[oc];
#pragma unroll
            for (int i = 0; i < MI; ++i) {
                int rbase = gm0 + (mhalf * MI + i) * 16 + (lane >> 4) * 4;
#pragma unroll
                for (int r = 0; r < 4; ++r) {
                    int rowc = rbase + r; if (rowc >= M) rowc = M - 1;
                    float rv = resb ? bf2f(resb[(size_t)rowc * HID + oc])
                                    : resf[(size_t)rowc * HID + oc];
                    acc[i][j][r] += bj + rv;
                }
            }
        }
#pragma unroll
        for (int i = 0; i < MI; ++i) {
#pragma unroll
            for (int r = 0; r < 4; ++r) {
                float s1 = acc[i][0][r] + acc[i][1][r] + acc[i][2][r] + acc[i][3][r];
                float s2 = acc[i][0][r] * acc[i][0][r] + acc[i][1][r] * acc[i][1][r]
                         + acc[i][2][r] * acc[i][2][r] + acc[i][3][r] * acc[i][3][r];
                s1 += __shfl_xor(s1, 1); s1 += __shfl_xor(s1, 2);
                s1 += __shfl_xor(s1, 4); s1 += __shfl_xor(s1, 8);
                s2 += __shfl_xor(s2, 1); s2 += __shfl_xor(s2, 2);
                s2 += __shfl_xor(s2, 4); s2 += __shfl_xor(s2, 8);
                if ((lane & 15) == 0) {
                    int rl = (mhalf * MI + i) * 16 + (lane >> 4) * 4 + r;
                    pS[rl][ohalf] = s1;
                    pQ[rl][ohalf] = s2;
                }
            }
        }
        __syncthreads();
#pragma unroll
        for (int i = 0; i < MI; ++i) {
#pragma unroll
            for (int r = 0; r < 4; ++r) {
                int rl = (mhalf * MI + i) * 16 + (lane >> 4) * 4 + r;
                float S = pS[rl][0] + pS[rl][1];
                float Q = pQ[rl][0] + pQ[rl][1];
                float mu = S * (1.f / 128.f);
                float var = Q * (1.f / 128.f) - mu * mu;
                float rstd = rsqrtf(var + 1e-5f);
#pragma unroll
                for (int j = 0; j < 4; ++j) {
                    int oc = (ohalf * 4 + j) * 16 + (lane & 15);
                    acc[i][j][r] = (acc[i][j][r] - mu) * rstd * g[oc] + be[oc];
                }
            }
        }
        __syncthreads();
    }

    if (OUTF == 0 || (OUTF == 3 && blockIdx.y == 0)) {
#pragma unroll
        for (int i = 0; i < MI; ++i)
#pragma unroll
            for (int j = 0; j < 4; ++j) {
                int oc = (ohalf * 4 + j) * 16 + (lane & 15);
                float bj = LN ? 0.f : bias[o0 + oc];
#pragma unroll
                for (int r = 0; r < 4; ++r) {
                    int rl = (mhalf * MI + i) * 16 + (lane >> 4) * 4 + r;
                    float v = acc[i][j][r] + bj;
                    if (ACT) v = gelu_f(v);
                    B16[rl * 136 + oc] = f2bf(v);
                }
            }
        __syncthreads();
        const int oo = (OUTF == 3) ? 0 : o0;
#pragma unroll
        for (int p = 0; p < MT / 16; ++p) {
            int row = p * 16 + (tid >> 4);
            int ch  = tid & 15;
            if (gm0 + row < M)
                *(short8*)&outb[(size_t)(gm0 + row) * ostride + oo + ch * 8] =
                    *(const short8*)&B16[row * 136 + ch * 8];
        }
        if (LN && hfragp) {
            // emit h-frag image: [tile16][4 kst][64 lane][8] (coalesced 1KB/wave)
            int kst = tid >> 6, ln = tid & 63;
#pragma unroll
            for (int p = 0; p < MT / 16; ++p) {
                if (gm0 + p * 16 < M) {
                    int gt = (gm0 >> 4) + p;
                    short8 v = *(const short8*)&B16[(p * 16 + (ln & 15)) * 136
                                                    + kst * 32 + (ln >> 4) * 8];
                    *(short8*)&hfragp[(((size_t)gt * 4 + kst) * 64 + ln) * 8] = v;
                }
            }
        }
    } else if (OUTF == 3) {
        // fp8 e4m3 out with x64 scale, into interleaved kv chunks of 512B row
#pragma unroll
        for (int i = 0; i < MI; ++i)
#pragma unroll
            for (int j = 0; j < 4; ++j) {
                int oc = (ohalf * 4 + j) * 16 + (lane & 15);
                float bj = bias[o0 + oc];
#pragma unroll
                for (int r = 0; r < 4; ++r) {
                    int rl = (mhalf * MI + i) * 16 + (lane >> 4) * 4 + r;
                    float v = (acc[i][j][r] + bj) * KV_SCALE;
                    B16[rl * 136 + oc] = f2bf(v);
                }
            }
        __syncthreads();
        const int koff = (blockIdx.y - 1) * 8;
#pragma unroll
        for (int p = 0; p < MT / 16; ++p) {
            int row = p * 16 + (tid >> 4);
            int ch  = tid & 15;
            if (gm0 + row < M) {
                short8 s = *(const short8*)&B16[row * 136 + ch * 8];
                unsigned u0 = 0, u1 = 0;
                u0 = __builtin_amdgcn_cvt_pk_fp8_f32(
                         bf2f((ushort_t)s[0]), bf2f((ushort_t)s[1]), u0, false);
                u0 = __builtin_amdgcn_cvt_pk_fp8_f32(
                         bf2f((ushort_t)s[2]), bf2f((ushort_t)s[3]), u0, true);
                u1 = __builtin_amdgcn_cvt_pk_fp8_f32(
                         bf2f((ushort_t)s[4]), bf2f((ushort_t)s[5]), u1, false);
                u1 = __builtin_amdgcn_cvt_pk_fp8_f32(
                         bf2f((ushort_t)s[6]), bf2f((ushort_t)s[7]), u1, true);
                uint2 o; o.x = u0; o.y = u1;
                *(uint2*)((char*)outb + (size_t)(gm0 + row) * QKV_ROWB
                          + 256 + ch * 16 + koff) = o;
            }
        }
    }
}

// ---------------- FF1: wave-independent frag GEMM + GELU -> a1 fp8 image -----
// Block = 4 independent waves (no barriers), block b owns rows [b*32, b*32+32),
// wave = ff-col group cg (128 cols each). All frag loads are single coalesced
// wave segments from pre-permuted images.
__global__ __launch_bounds__(256)
void ff1w_kernel(const ushort_t* __restrict__ hfrag,
                 const ushort_t* __restrict__ w1frag,
                 const float* __restrict__ b1,
                 unsigned char* __restrict__ a1img, int M)
{
    __shared__ __align__(16) ushort_t sT[4][16 * 136];   // per-wave transpose buf
    const int wave = threadIdx.x >> 6, lane = threadIdx.x & 63;
    const int cg = wave;
    const int nt16 = (M + 15) / 16;
    const int gt0 = blockIdx.x * 2;
    const int gt1 = gt0 + 1;
    const int gt1c = (gt1 < nt16) ? gt1 : nt16 - 1;
    const int l15 = lane & 15, l4 = lane >> 4;

    floatx4 acc[2][8];
#pragma unroll
    for (int i = 0; i < 2; ++i)
#pragma unroll
        for (int j = 0; j < 8; ++j) acc[i][j] = (floatx4)(0.f);

#pragma unroll
    for (int kst = 0; kst < 4; ++kst) {
        short8 a0 = *(const short8*)&hfrag[(((size_t)gt0  * 4 + kst) * 64 + lane) * 8];
        short8 a1 = *(const short8*)&hfrag[(((size_t)gt1c * 4 + kst) * 64 + lane) * 8];
        short8 bv[8];
#pragma unroll
        for (int j = 0; j < 8; ++j)
            bv[j] = *(const short8*)&w1frag[((((size_t)cg * 8 + j) * 4 + kst) * 64 + lane) * 8];
#pragma unroll
        for (int j = 0; j < 8; ++j) {
            acc[0][j] = __builtin_amdgcn_mfma_f32_16x16x32_bf16(a0, bv[j], acc[0][j], 0, 0, 0);
            acc[1][j] = __builtin_amdgcn_mfma_f32_16x16x32_bf16(a1, bv[j], acc[1][j], 0, 0, 0);
        }
    }

    float b1v[8];
#pragma unroll
    for (int j = 0; j < 8; ++j) b1v[j] = b1[cg * 128 + j * 16 + l15];

#pragma unroll
    for (int i = 0; i < 2; ++i) {
        const int gt = i ? gt1 : gt0;
        // C/D tile -> row-major sT (per-wave; wave-internal ordering only)
#pragma unroll
        for (int j = 0; j < 8; ++j)
#pragma unroll
            for (int r = 0; r < 4; ++r)
                sT[wave][(l4 * 4 + r) * 136 + j * 16 + l15] =
                    f2bf(gelu_f(acc[i][j][r] + b1v[j]));
        if (gt < nt16) {
#pragma unroll
            for (int q = 0; q < 4; ++q) {
                float v[8];
#pragma unroll
                for (int e = 0; e < 8; ++e)
                    v[e] = bf2f(sT[wave][l15 * 136 + q * 32 + l4 * 8 + e]) * A1_SCALE;
                unsigned u0 = 0, u1 = 0;
                u0 = __builtin_amdgcn_cvt_pk_fp8_f32(v[0], v[1], u0, false);
                u0 = __builtin_amdgcn_cvt_pk_fp8_f32(v[2], v[3], u0, true);
                u1 = __builtin_amdgcn_cvt_pk_fp8_f32(v[4], v[5], u1, false);
                u1 = __builtin_amdgcn_cvt_pk_fp8_f32(v[6], v[7], u1, true);
                uint2 o; o.x = u0; o.y = u1;
                *(uint2*)(a1img + (((size_t)gt * 16 + cg * 4 + q) * 64 + lane) * 8) = o;
            }
        }
    }
}

// ---------------- FF2: wave-independent fp8 frag GEMM + residual + LN2 -------
// Wave w (global) owns rows [w*32, +32): 256 fp8 MFMAs, 160 coalesced loads.
__global__ __launch_bounds__(256)
void ff2w_kernel(const unsigned char* __restrict__ a1img,
                 const unsigned char* __restrict__ w2frag8,
                 const ushort_t* __restrict__ hb,
                 const float* __restrict__ b2,
                 const float* __restrict__ g, const float* __restrict__ be,
                 float* __restrict__ out, int M)
{
    const int wave = threadIdx.x >> 6, lane = threadIdx.x & 63;
    const int t32 = blockIdx.x * 4 + wave;
    const int nt32 = (M + 31) / 32;
    if (t32 >= nt32) return;
    const int nt16 = (M + 15) / 16;
    const int gt0 = t32 * 2;
    const int gt1c = (gt0 + 1 < nt16) ? gt0 + 1 : nt16 - 1;
    const int l15 = lane & 15, l4 = lane >> 4;

    floatx4 acc[2][8];
#pragma unroll
    for (int i = 0; i < 2; ++i)
#pragma unroll
        for (int j = 0; j < 8; ++j) acc[i][j] = (floatx4)(0.f);

#pragma unroll
    for (int kst = 0; kst < 16; ++kst) {
        long a0 = *(const long*)(a1img + (((size_t)gt0  * 16 + kst) * 64 + lane) * 8);
        long a1 = *(const long*)(a1img + (((size_t)gt1c * 16 + kst) * 64 + lane) * 8);
        long bv[8];
#pragma unroll
        for (int j = 0; j < 8; ++j)
            bv[j] = *(const long*)(w2frag8 + (((size_t)j * 16 + kst) * 64 + lane) * 8);
#pragma unroll
        for (int j = 0; j < 8; ++j) {
            acc[0][j] = __builtin_amdgcn_mfma_f32_16x16x32_fp8_fp8(a0, bv[j], acc[0][j], 0, 0, 0);
            acc[1][j] = __builtin_amdgcn_mfma_f32_16x16x32_fp8_fp8(a1, bv[j], acc[1][j], 0, 0, 0);
        }
    }

    float b2v[8], gv[8], bev[8];
#pragma unroll
    for (int j = 0; j < 8; ++j) {
        int oc = j * 16 + l15;
        b2v[j] = b2[oc]; gv[j] = g[oc]; bev[j] = be[oc];
    }

#pragma unroll
    for (int i = 0; i < 2; ++i) {
        const int rb = (t32 * 2 + i) * 16;
#pragma unroll
        for (int j = 0; j < 8; ++j) {
            int oc = j * 16 + l15;
#pragma unroll
            for (int r = 0; r < 4; ++r) {
                int row = rb + l4 * 4 + r;
                int rc = (row < M) ? row : M - 1;
                acc[i][j][r] = acc[i][j][r] * FF2_DESCALE + b2v[j]
                             + bf2f(hb[(size_t)rc * HID + oc]);
            }
        }
#pragma unroll
        for (int r = 0; r < 4; ++r) {
            float s1 = 0.f, s2 = 0.f;
#pragma unroll
            for (int j = 0; j < 8; ++j) {
                s1 += acc[i][j][r];
                s2 += acc[i][j][r] * acc[i][j][r];
            }
            s1 += __shfl_xor(s1, 1); s1 += __shfl_xor(s1, 2);
            s1 += __shfl_xor(s1, 4); s1 += __shfl_xor(s1, 8);
            s2 += __shfl_xor(s2, 1); s2 += __shfl_xor(s2, 2);
            s2 += __shfl_xor(s2, 4); s2 += __shfl_xor(s2, 8);
            float mu = s1 * (1.f / 128.f);
            float var = s2 * (1.f / 128.f) - mu * mu;
            float rstd = rsqrtf(var + 1e-5f);
            int row = rb + l4 * 4 + r;
            if (row < M) {
#pragma unroll
                for (int j = 0; j < 8; ++j)
                    out[(size_t)row * HID + j * 16 + l15] =
                        (acc[i][j][r] - mu) * rstd * gv[j] + bev[j];
            }
        }
    }
}

// ---------------- counting-sort scan chain ----------------------------------
__global__ __launch_bounds__(256)
void scan1_kernel(const int* __restrict__ cnt, int* __restrict__ parts, int N)
{
    __shared__ int sd[256];
    int t = threadIdx.x;
    int base = blockIdx.x * 1024 + t * 4;
    int s = 0;
#pragma unroll
    for (int j = 0; j < 4; ++j) if (base + j < N) s += cnt[base + j];
    sd[t] = s; __syncthreads();
    for (int off = 128; off; off >>= 1) {
        if (t < off) sd[t] += sd[t + off];
        __syncthreads();
    }
    if (t == 0) parts[blockIdx.x] = sd[0];
}

__global__ __launch_bounds__(256)
void scan2_kernel(const int* __restrict__ parts, int* __restrict__ poff, int nb)
{
    __shared__ int sd[256];
    int t = threadIdx.x;
    int v = (t < nb) ? parts[t] : 0;
    sd[t] = v; __syncthreads();
    for (int off = 1; off < 256; off <<= 1) {
        int u = (t >= off) ? sd[t - off] : 0;
        __syncthreads();
        sd[t] += u;
        __syncthreads();
    }
    if (t < nb) poff[t] = sd[t] - v;   // exclusive
}

__global__ __launch_bounds__(256)
void scan3_kernel(const int* __restrict__ cnt, const int* __restrict__ poff,
                  int* __restrict__ rp, int N)
{
    __shared__ int sd[256];
    int t = threadIdx.x;
    int base = blockIdx.x * 1024 + t * 4;
    int v0 = (base + 0 < N) ? cnt[base + 0] : 0;
    int v1 = (base + 1 < N) ? cnt[base + 1] : 0;
    int v2 = (base + 2 < N) ? cnt[base + 2] : 0;
    int v3 = (base + 3 < N) ? cnt[base + 3] : 0;
    int s = v0 + v1 + v2 + v3;
    sd[t] = s; __syncthreads();
    for (int off = 1; off < 256; off <<= 1) {
        int u = (t >= off) ? sd[t - off] : 0;
        __syncthreads();
        sd[t] += u;
        __syncthreads();
    }
    int o = poff[blockIdx.x] + sd[t] - s;
    if (base + 0 < N) rp[base + 0] = o;
    if (base + 1 < N) rp[base + 1] = o + v0;
    if (base + 2 < N) rp[base + 2] = o + v0 + v1;
    if (base + 3 < N) rp[base + 3] = o + v0 + v1 + v2;
}

// cohort scatter: blockIdx.x & 7 keys the XCD; each cohort owns 1/8 of nodes.
__global__ __launch_bounds__(256)
void scatter_kernel(const int* __restrict__ src, const int* __restrict__ dst,
                    int* __restrict__ rp, int* __restrict__ ssrc, int E, int N)
{
    int coh = blockIdx.x & 7;
    int bc  = blockIdx.x >> 3;
    int rr  = (N + 7) >> 3;
    int nlo = coh * rr;
    int nhi = nlo + rr; if (nhi > N) nhi = N;
    int stride = (gridDim.x >> 3) * 256;
    for (int e = bc * 256 + threadIdx.x; e < E; e += stride) {
        int d = dst[e];
        if (d >= nlo && d < nhi) {
            int pos = atomicAdd(&rp[d], 1);
            ssrc[pos] = src[e];
        }
    }
}

// ---------------- fused attention: 4 edges per wave-step ---------------------
__global__ __launch_bounds__(256)
void attn_fused_kernel(const ushort_t* __restrict__ qkvb, const int* __restrict__ rp,
                       const int* __restrict__ ssrc, ushort_t* __restrict__ aggb, int N)
{
    int wave = threadIdx.x >> 6, lane = threadIdx.x & 63;
    int n = blockIdx.x * 4 + wave;
    if (n >= N) return;
    int grp = lane >> 4;            // 0..3 edge slot
    int cb  = (lane & 15) * 16;     // byte offset of this lane's 16B chunk
    const char* base = (const char*)qkvb;

    short8 qv = *(const short8*)(base + n * QKV_ROWB + cb);
    float q[8];
#pragma unroll
    for (int j = 0; j < 8; ++j) q[j] = bf2f((ushort_t)qv[j]) * (0.25f / KV_SCALE);

    int r0 = n ? rp[n - 1] : 0;
    int r1 = rp[n];
    float acc[8] = {0.f, 0.f, 0.f, 0.f, 0.f, 0.f, 0.f, 0.f};
    float l = 0.f;

    int r = r0;
    for (; r + 8 <= r1; r += 8) {
        int s0 = ssrc[r + grp];
        int s1 = ssrc[r + 4 + grp];
        uint4 kv0 = *(const uint4*)(base + s0 * QKV_ROWB + 256 + cb);
        uint4 kv1 = *(const uint4*)(base + s1 * QKV_ROWB + 256 + cb);

        f32x2 a0 = __builtin_amdgcn_cvt_pk_f32_fp8(kv0.x, false);
        f32x2 a1 = __builtin_amdgcn_cvt_pk_f32_fp8(kv0.x, true);
        f32x2 a2 = __builtin_amdgcn_cvt_pk_f32_fp8(kv0.y, false);
        f32x2 a3 = __builtin_amdgcn_cvt_pk_f32_fp8(kv0.y, true);
        f32x2 b0 = __builtin_amdgcn_cvt_pk_f32_fp8(kv1.x, false);
        f32x2 b1 = __builtin_amdgcn_cvt_pk_f32_fp8(kv1.x, true);
        f32x2 b2 = __builtin_amdgcn_cvt_pk_f32_fp8(kv1.y, false);
        f32x2 b3 = __builtin_amdgcn_cvt_pk_f32_fp8(kv1.y, true);

        float p0 = 0.f, p1 = 0.f;
        p0 = fmaf(q[0], a0.x, p0); p0 = fmaf(q[1], a0.y, p0);
        p0 = fmaf(q[2], a1.x, p0); p0 = fmaf(q[3], a1.y, p0);
        p0 = fmaf(q[4], a2.x, p0); p0 = fmaf(q[5], a2.y, p0);
        p0 = fmaf(q[6], a3.x, p0); p0 = fmaf(q[7], a3.y, p0);
        p1 = fmaf(q[0], b0.x, p1); p1 = fmaf(q[1], b0.y, p1);
        p1 = fmaf(q[2], b1.x, p1); p1 = fmaf(q[3], b1.y, p1);
        p1 = fmaf(q[4], b2.x, p1); p1 = fmaf(q[5], b2.y, p1);
        p1 = fmaf(q[6], b3.x, p1); p1 = fmaf(q[7], b3.y, p1);

        p0 += __shfl_xor(p0, 1);
        p1 += __shfl_xor(p1, 1);
        float e0 = __expf(p0), e1 = __expf(p1);
        l += e0 + e1;

        f32x2 v0 = __builtin_amdgcn_cvt_pk_f32_fp8(kv0.z, false);
        f32x2 v1 = __builtin_amdgcn_cvt_pk_f32_fp8(kv0.z, true);
        f32x2 v2 = __builtin_amdgcn_cvt_pk_f32_fp8(kv0.w, false);
        f32x2 v3 = __builtin_amdgcn_cvt_pk_f32_fp8(kv0.w, true);
        f32x2 w0 = __builtin_amdgcn_cvt_pk_f32_fp8(kv1.z, false);
        f32x2 w1 = __builtin_amdgcn_cvt_pk_f32_fp8(kv1.z, true);
        f32x2 w2 = __builtin_amdgcn_cvt_pk_f32_fp8(kv1.w, false);
        f32x2 w3 = __builtin_amdgcn_cvt_pk_f32_fp8(kv1.w, true);

        acc[0] = fmaf(e0, v0.x, acc[0]); acc[1] = fmaf(e0, v0.y, acc[1]);
        acc[2] = fmaf(e0, v1.x, acc[2]); acc[3] = fmaf(e0, v1.y, acc[3]);
        acc[4] = fmaf(e0, v2.x, acc[4]); acc[5] = fmaf(e0, v2.y, acc[5]);
        acc[6] = fmaf(e0, v3.x, acc[6]); acc[7] = fmaf(e0, v3.y, acc[7]);
        acc[0] = fmaf(e1, w0.x, acc[0]); acc[1] = fmaf(e1, w0.y, acc[1]);
        acc[2] = fmaf(e1, w1.x, acc[2]); acc[3] = fmaf(e1, w1.y, acc[3]);
        acc[4] = fmaf(e1, w2.x, acc[4]); acc[5] = fmaf(e1, w2.y, acc[5]);
        acc[6] = fmaf(e1, w3.x, acc[6]); acc[7] = fmaf(e1, w3.y, acc[7]);
    }
    for (; r < r1; r += 4) {
        int e = r + grp;
        int s = ssrc[(e < r1) ? e : r0];
        uint4 kv = *(const uint4*)(base + s * QKV_ROWB + 256 + cb);
        f32x2 a0 = __builtin_amdgcn_cvt_pk_f32_fp8(kv.x, false);
        f32x2 a1 = __builtin_amdgcn_cvt_pk_f32_fp8(kv.x, true);
        f32x2 a2 = __builtin_amdgcn_cvt_pk_f32_fp8(kv.y, false);
        f32x2 a3 = __builtin_amdgcn_cvt_pk_f32_fp8(kv.y, true);
        float p = 0.f;
        p = fmaf(q[0], a0.x, p); p = fmaf(q[1], a0.y, p);
        p = fmaf(q[2], a1.x, p); p = fmaf(q[3], a1.y, p);
        p = fmaf(q[4], a2.x, p); p = fmaf(q[5], a2.y, p);
        p = fmaf(q[6], a3.x, p); p = fmaf(q[7], a3.y, p);
        p += __shfl_xor(p, 1);
        float ea = (e < r1) ? __expf(p) : 0.f;
        l += ea;
        f32x2 v0 = __builtin_amdgcn_cvt_pk_f32_fp8(kv.z, false);
        f32x2 v1 = __builtin_amdgcn_cvt_pk_f32_fp8(kv.z, true);
        f32x2 v2 = __builtin_amdgcn_cvt_pk_f32_fp8(kv.w, false);
        f32x2 v3 = __builtin_amdgcn_cvt_pk_f32_fp8(kv.w, true);
        acc[0] = fmaf(ea, v0.x, acc[0]); acc[1] = fmaf(ea, v0.y, acc[1]);
        acc[2] = fmaf(ea, v1.x, acc[2]); acc[3] = fmaf(ea, v1.y, acc[3]);
        acc[4] = fmaf(ea, v2.x, acc[4]); acc[5] = fmaf(ea, v2.y, acc[5]);
        acc[6] = fmaf(ea, v3.x, acc[6]); acc[7] = fmaf(ea, v3.y, acc[7]);
    }

#pragma unroll
    for (int j = 0; j < 8; ++j) {
        acc[j] += __shfl_xor(acc[j], 16);
        acc[j] += __shfl_xor(acc[j], 32);
    }
    l += __shfl_xor(l, 16);
    l += __shfl_xor(l, 32);
    float inv = KV_INV_SCALE / (l + 1e-16f);
    if (grp == 0) {
        short8 o;
#pragma unroll
        for (int j = 0; j < 8; ++j) o[j] = (short)f2bf(acc[j] * inv);
        *(short8*)((char*)aggb + n * 256 + cb) = o;
    }
}

// ============================================================================
extern "C" void kernel_launch(void* const* d_in, const int* in_sizes, int n_in,
                              void* d_out, int out_size, void* d_ws, size_t ws_size,
                              hipStream_t stream)
{
    const float* x  = (const float*)d_in[0];
    const int*   ei = (const int*)d_in[1];
    const float* Wq = (const float*)d_in[2];
    const float* bq = (const float*)d_in[3];
    const float* Wk = (const float*)d_in[4];
    const float* bk = (const float*)d_in[5];
    const float* Wv = (const float*)d_in[6];
    const float* bv = (const float*)d_in[7];
    const float* Wo = (const float*)d_in[8];
    const float* bo = (const float*)d_in[9];
    const float* W1 = (const float*)d_in[10];
    const float* b1 = (const float*)d_in[11];
    const float* W2 = (const float*)d_in[12];
    const float* b2 = (const float*)d_in[13];
    const float* g1 = (const float*)d_in[14];
    const float* be1= (const float*)d_in[15];
    const float* g2 = (const float*)d_in[16];
    const float* be2= (const float*)d_in[17];
    float* out = (float*)d_out;

    const int N = in_sizes[0] / HID;      // 50000
    const int E = in_sizes[1] / 2;        // 800000
    const int* srcp = ei;
    const int* dstp = ei + E;

    const size_t NH = (size_t)N * HID;    // 6.4M
    float* wsf = (float*)d_ws;

    // ---- workspace layout (f32 units) ----
    ushort_t* xb    = (ushort_t*)wsf;                 // [0, 0.5NH)  dies after QKV
    ushort_t* qkvb  = (ushort_t*)(wsf + NH / 2);      // [0.5, 1.5)  dies after attn
    ushort_t* hfrag = (ushort_t*)(wsf + NH + NH / 2); // [1.5, 2.0)  h frag image
    ushort_t* aggb  = (ushort_t*)(wsf + 2 * NH);      // [2.0, 2.5)  dies after Wo
    ushort_t* hb    = (ushort_t*)wsf;                 // [0, 0.5)    overlays dead xb
    unsigned char* a1img = (unsigned char*)(wsf + NH / 2); // [0.5,1.5) overlays dead qkvb

    ushort_t* wts    = (ushort_t*)(wsf + 2 * NH + NH / 2); // Wq..Wo bf16: 65536
    ushort_t* w1frag = wts + 65536;                        // 65536 ushort
    unsigned char* w2frag8 = (unsigned char*)(w1frag + 65536); // 65536 B
    float*    bqkv = (float*)(w2frag8 + 65536);            // 384 f32
    int*      rp   = (int*)(bqkv + 384);                   // N+1
    int*      cnt  = rp + (N + 1);                         // N
    int*      poff = cnt + N;                              // 256
    int*      parts= poff + 256;                           // 256
    int*      ssrc = parts + 256;                          // E

    // ---- prep (+fused degree count; cnt zeroed first) ----
    hipMemsetAsync(cnt, 0, N * sizeof(int), stream);
    const int xpairs = (int)(NH / 2);
    const int ptot   = xpairs + 32768 + 384 + 8192 + 8192 + E;
    prep_kernel<<<(ptot + 255) / 256, 256, 0, stream>>>(
        x, Wq, Wk, Wv, Wo, W1, W2, bq, bk, bv, dstp, cnt, E,
        xb, wts, bqkv, w1frag, w2frag8, xpairs);

    // ---- counting sort of edges by dst ----
    const int nb = (N + 1023) / 1024;   // 49
    scan1_kernel<<<nb, 256, 0, stream>>>(cnt, parts, N);
    scan2_kernel<<<1, 256, 0, stream>>>(parts, poff, nb);
    scan3_kernel<<<nb, 256, 0, stream>>>(cnt, poff, rp, N);
    scatter_kernel<<<2048, 256, 0, stream>>>(srcp, dstp, rp, ssrc, E, N);

    const int gx64 = (N + 63) / 64;     // 782
    const int nt32 = (N + 31) / 32;     // 1563

    // ---- merged QKV: y=0 -> q bf16, y=1/2 -> k/v fp8 ----
    gemm_t<64, 0, 0, 3><<<dim3(gx64, 3), 256, 0, stream>>>(
        xb, HID, N, wts, HID, bqkv, nullptr, qkvb, 256,
        nullptr, nullptr, nullptr, nullptr);

    // ---- fused attention ----
    attn_fused_kernel<<<(N + 3) / 4, 256, 0, stream>>>(qkvb, rp, ssrc, aggb, N);

    // ---- Wo + residual(x) + LN1 -> hb (bf16) + hfrag (frag image) ----
    gemm_t<64, 0, 1, 0><<<dim3(gx64, 1), 256, 0, stream>>>(
        aggb, HID, N, wts + 49152, HID, bo, hfrag, hb, HID,
        x, nullptr, g1, be1);

    // ---- FF1 (frag images, wave-independent) -> a1 fp8 image ----
    ff1w_kernel<<<nt32, 256, 0, stream>>>(hfrag, w1frag, b1, a1img, N);

    // ---- FF2 (fp8 frag GEMM) + residual(hb) + LN2 -> out (f32) ----
    ff2w_kernel<<<(nt32 + 3) / 4, 256, 0, stream>>>(
        a1img, w2frag8, hb, b2, g2, be2, out, N);
}

// Round 8
// 322.414 us; speedup vs baseline: 1.3518x; 1.0047x over previous
//
#include <hip/hip_runtime.h>
#include <math.h>

#define N_HEADS 8
#define HEAD_DIM 16
#define HID 128
// qkv row: 256B q (bf16) + 16 x [8B k fp8 | 8B v fp8] = 512B
#define QKV_ROWB 512

typedef unsigned short ushort_t;
typedef __attribute__((ext_vector_type(8))) short short8;
typedef __attribute__((ext_vector_type(4))) float floatx4;
typedef __attribute__((ext_vector_type(2))) float f32x2;

#define KV_SCALE 64.0f
#define KV_INV_SCALE 0.015625f

// FF fp8 scales: W2 x 2^16, a1 x 2^9
#define W2_SCALE 65536.0f
#define A1_SCALE 512.0f
#define FF2_DESCALE (1.0f / 33554432.0f)   // 1/(512*65536)

__device__ __forceinline__ ushort_t f2bf(float f) {
    unsigned u = __float_as_uint(f);
    unsigned r = (u + 0x7FFFu + ((u >> 16) & 1u)) >> 16;
    return (ushort_t)r;
}
__device__ __forceinline__ float bf2f(ushort_t u) {
    return __uint_as_float(((unsigned)u) << 16);
}

__device__ __forceinline__ void gld_lds16(const void* g, void* l) {
    __builtin_amdgcn_global_load_lds(
        (const __attribute__((address_space(1))) void*)g,
        (__attribute__((address_space(3))) void*)l, 16, 0, 0);
}

// fast exact-GELU: erf via Abramowitz-Stegun 7.1.26 (|err| <= 1.5e-7)
__device__ __forceinline__ float gelu_f(float x) {
    float z = fabsf(x) * 0.70710678118654752f;
    float t = 1.0f / (1.0f + 0.3275911f * z);
    float y = t * (0.254829592f + t * (-0.284496736f + t * (1.421413741f
            + t * (-1.453152027f + t * 1.061405429f))));
    float e = 1.0f - y * __expf(-z * z);
    e = copysignf(e, x);
    return 0.5f * x * (1.0f + e);
}

// ---- prep: x frag image, Wo bf16, Wq/Wk/Wv frag, W1 frag, W2 fp8 frag, bias -
// frag layout (16x16x32 MFMA A/B): [tile16][kst][lane][8]; elem =
// (row = t16*16 + (lane&15), k = kst*32 + (lane>>4)*8 + e). One wave frag
// load at runtime is a single coalesced 512B/1KB segment.
__global__ __launch_bounds__(256)
void prep_kernel(const float* __restrict__ x,
                 const float* __restrict__ Wq, const float* __restrict__ Wk,
                 const float* __restrict__ Wv, const float* __restrict__ Wo,
                 const float* __restrict__ W1, const float* __restrict__ W2,
                 const float* __restrict__ bq, const float* __restrict__ bk,
                 const float* __restrict__ bv,
                 ushort_t* __restrict__ xfrag, ushort_t* __restrict__ woB,
                 ushort_t* __restrict__ wqkvf,
                 ushort_t* __restrict__ w1frag,
                 unsigned char* __restrict__ w2frag8,
                 float* __restrict__ bqkv, int xchunks)
{
    int i = blockIdx.x * 256 + threadIdx.x;
    if (i < xchunks) {                      // x -> frag image (8 f32 -> 8 bf16)
        int t16 = i >> 8;
        int rem = i & 255;
        int lane = rem & 63;
        int row = t16 * 16 + (lane & 15);
        int k   = (rem >> 6) * 32 + (lane >> 4) * 8;
        const float* s = x + (size_t)row * HID + k;
        short8 v;
#pragma unroll
        for (int e = 0; e < 8; ++e) v[e] = (short)f2bf(s[e]);
        *(short8*)(xfrag + (size_t)i * 8) = v;
        return;
    }
    int j = i - xchunks;
    if (j < 8192) {                         // Wo -> bf16 row-major (float2/thread)
        float2 v = ((const float2*)Wo)[j];
        woB[j * 2]     = f2bf(v.x);
        woB[j * 2 + 1] = f2bf(v.y);
        return;
    }
    int b = j - 8192;
    if (b < 6144) {                         // Wq/Wk/Wv frag: 3 x [8][4][64][8]
        int w = b >> 11;
        int rem = b & 2047;
        int t16 = rem >> 8;
        int rem2 = rem & 255;
        int lane = rem2 & 63;
        int row = t16 * 16 + (lane & 15);
        int k   = ((rem2 >> 6) & 3) * 32 + (lane >> 4) * 8;
        const float* W = (w == 0) ? Wq : (w == 1) ? Wk : Wv;
        const float* s = W + (size_t)row * HID + k;
        short8 v;
#pragma unroll
        for (int e = 0; e < 8; ++e) v[e] = (short)f2bf(s[e]);
        *(short8*)(wqkvf + (size_t)b * 8) = v;
        return;
    }
    int c = b - 6144;
    if (c < 8192) {                         // W1-frag bf16: [32 t16][4 kst][64][8]
        int lane = c & 63, tk = c >> 6;
        int t16 = tk >> 2, kst = tk & 3;
        int row = t16 * 16 + (lane & 15);
        int kb  = kst * 32 + (lane >> 4) * 8;
        const float* s = W1 + (size_t)row * HID + kb;
        short8 v;
#pragma unroll
        for (int e = 0; e < 8; ++e) v[e] = (short)f2bf(s[e]);
        *(short8*)(w1frag + (size_t)c * 8) = v;
        return;
    }
    int c2 = c - 8192;
    if (c2 < 8192) {                        // W2-frag fp8 x2^16: [8 t16][16 kst][64][8]
        int lane = c2 & 63, tk = c2 >> 6;
        int t16 = tk >> 4, kst = tk & 15;
        int row = t16 * 16 + (lane & 15);
        int kb  = kst * 32 + (lane >> 4) * 8;
        const float* s = W2 + (size_t)row * 512 + kb;
        unsigned u0 = 0, u1 = 0;
        u0 = __builtin_amdgcn_cvt_pk_fp8_f32(s[0]*W2_SCALE, s[1]*W2_SCALE, u0, false);
        u0 = __builtin_amdgcn_cvt_pk_fp8_f32(s[2]*W2_SCALE, s[3]*W2_SCALE, u0, true);
        u1 = __builtin_amdgcn_cvt_pk_fp8_f32(s[4]*W2_SCALE, s[5]*W2_SCALE, u1, false);
        u1 = __builtin_amdgcn_cvt_pk_fp8_f32(s[6]*W2_SCALE, s[7]*W2_SCALE, u1, true);
        uint2 o; o.x = u0; o.y = u1;
        *(uint2*)(w2frag8 + (size_t)c2 * 8) = o;
        return;
    }
    int d = c2 - 8192;
    if (d < 384) {
        bqkv[d] = (d < 128) ? bq[d] : (d < 256) ? bk[d - 128] : bv[d - 256];
    }
}

// cohort degree count: blockIdx.x & 7 keys the XCD; each cohort counts only
// its 1/8 node range -> cnt lines stay within ONE L2 (mirrors scatter fix).
__global__ __launch_bounds__(256)
void count_kernel(const int* __restrict__ dst, int* __restrict__ cnt, int E, int N)
{
    int coh = blockIdx.x & 7;
    int bc  = blockIdx.x >> 3;
    int rr  = (N + 7) >> 3;
    int nlo = coh * rr;
    int nhi = nlo + rr; if (nhi > N) nhi = N;
    int stride = (gridDim.x >> 3) * 256;
    for (int e = bc * 256 + threadIdx.x; e < E; e += stride) {
        int d = dst[e];
        if (d >= nlo && d < nhi) atomicAdd(&cnt[d], 1);
    }
}

// ---------------- QKV: wave-independent frag GEMM ----------------------------
// grid (ceil(nt16/8), 3): y picks q/k/v. Block = 4 independent waves, wave w
// owns row-tiles [bx*8+2w, +2). 64 MFMAs + 40 coalesced frag loads per wave,
// no barriers. Epilogue via per-wave sT transpose (ff1w-validated pattern).
__global__ __launch_bounds__(256)
void qkvw_kernel(const ushort_t* __restrict__ xfrag,
                 const ushort_t* __restrict__ wqkvf,
                 const float* __restrict__ bqkv,
                 ushort_t* __restrict__ qkvb, int nt16)
{
    __shared__ __align__(16) ushort_t sT[4][16 * 136];
    const int wave = threadIdx.x >> 6, lane = threadIdx.x & 63;
    const int y = blockIdx.y;
    const int l15 = lane & 15, l4 = lane >> 4;
    const int gt0 = blockIdx.x * 8 + wave * 2;
    const int gt0c = (gt0 < nt16) ? gt0 : nt16 - 1;
    const int gt1c = (gt0 + 1 < nt16) ? gt0 + 1 : nt16 - 1;

    floatx4 acc[2][8];
#pragma unroll
    for (int i = 0; i < 2; ++i)
#pragma unroll
        for (int j = 0; j < 8; ++j) acc[i][j] = (floatx4)(0.f);

    const ushort_t* wf = wqkvf + (size_t)y * 16384;
#pragma unroll
    for (int kst = 0; kst < 4; ++kst) {
        short8 a0 = *(const short8*)&xfrag[(((size_t)gt0c * 4 + kst) * 64 + lane) * 8];
        short8 a1 = *(const short8*)&xfrag[(((size_t)gt1c * 4 + kst) * 64 + lane) * 8];
        short8 bv[8];
#pragma unroll
        for (int j = 0; j < 8; ++j)
            bv[j] = *(const short8*)&wf[(((size_t)j * 4 + kst) * 64 + lane) * 8];
#pragma unroll
        for (int j = 0; j < 8; ++j) {
            acc[0][j] = __builtin_amdgcn_mfma_f32_16x16x32_bf16(a0, bv[j], acc[0][j], 0, 0, 0);
            acc[1][j] = __builtin_amdgcn_mfma_f32_16x16x32_bf16(a1, bv[j], acc[1][j], 0, 0, 0);
        }
    }

    float bb[8];
#pragma unroll
    for (int j = 0; j < 8; ++j) bb[j] = bqkv[y * 128 + j * 16 + l15];

#pragma unroll
    for (int i = 0; i < 2; ++i) {
        const int gt = gt0 + i;
        // C/D -> row-major sT (wave-internal only; same pattern as ff1w)
#pragma unroll
        for (int j = 0; j < 8; ++j)
#pragma unroll
            for (int r = 0; r < 4; ++r) {
                float v = acc[i][j][r] + bb[j];
                if (y) v *= KV_SCALE;
                sT[wave][(l4 * 4 + r) * 136 + j * 16 + l15] = f2bf(v);
            }
        if (gt < nt16) {
            if (y == 0) {
#pragma unroll
                for (int c = 0; c < 4; ++c) {
                    int ch = l4 * 4 + c;
                    *(short8*)&qkvb[(size_t)(gt * 16 + l15) * 256 + ch * 8] =
                        *(const short8*)&sT[wave][l15 * 136 + ch * 8];
                }
            } else {
                const int koff = (y - 1) * 8;
#pragma unroll
                for (int c = 0; c < 4; ++c) {
                    int ch = l4 * 4 + c;
                    short8 s = *(const short8*)&sT[wave][l15 * 136 + ch * 8];
                    unsigned u0 = 0, u1 = 0;
                    u0 = __builtin_amdgcn_cvt_pk_fp8_f32(
                             bf2f((ushort_t)s[0]), bf2f((ushort_t)s[1]), u0, false);
                    u0 = __builtin_amdgcn_cvt_pk_fp8_f32(
                             bf2f((ushort_t)s[2]), bf2f((ushort_t)s[3]), u0, true);
                    u1 = __builtin_amdgcn_cvt_pk_fp8_f32(
                             bf2f((ushort_t)s[4]), bf2f((ushort_t)s[5]), u1, false);
                    u1 = __builtin_amdgcn_cvt_pk_fp8_f32(
                             bf2f((ushort_t)s[6]), bf2f((ushort_t)s[7]), u1, true);
                    uint2 o; o.x = u0; o.y = u1;
                    *(uint2*)((char*)qkvb + (size_t)(gt * 16 + l15) * QKV_ROWB
                              + 256 + ch * 16 + koff) = o;
                }
            }
        }
    }
}

// ---------------- templated bf16 MFMA GEMM (MT=64, dbuf) — Wo only ----------
template<int MT, int ACT, int LN, int OUTF>
__global__ __launch_bounds__(256)
void gemm_t(const ushort_t* __restrict__ A, int lda, int M,
            const ushort_t* __restrict__ W, int K,
            const float* __restrict__ bias,
            ushort_t* __restrict__ hfragp, ushort_t* __restrict__ outb, int ostride,
            const float* __restrict__ resf, const ushort_t* __restrict__ resb,
            const float* __restrict__ g, const float* __restrict__ be)
{
    constexpr int MI   = MT / 32;
    constexpr int HALF = MT * 64 + 128 * 64;
    constexpr int BNC  = MT * 136;
    constexpr int SB   = (2 * HALF > BNC) ? 2 * HALF : BNC;
    __shared__ __align__(16) ushort_t sbuf[SB];
    __shared__ float pS[LN ? MT : 1][2];
    __shared__ float pQ[LN ? MT : 1][2];

    const int tid  = threadIdx.x;
    const int wave = tid >> 6, lane = tid & 63;
    const int gm0 = blockIdx.x * MT;
    const int o0  = blockIdx.y * 128;
    const int mhalf = wave >> 1, ohalf = wave & 1;

    auto stage = [&](int kc, int h) {
        ushort_t* As = sbuf + h * HALF;
        ushort_t* Ws = As + MT * 64;
#pragma unroll
        for (int it = 0; it < 4; ++it) {          // W tile 128x64
            int s   = it * 256 + tid;
            int ln  = s & 63;
            int grp = s >> 6;
            int tile = grp >> 1, kst = grp & 1;
            int row = tile * 16 + (ln & 15);
            int kk  = kst * 32 + (ln >> 4) * 8;
            gld_lds16(&W[(size_t)(o0 + row) * K + kc + kk],
                      &Ws[(it * 256 + wave * 64) * 8]);
        }
#pragma unroll
        for (int it = 0; it < MT / 32; ++it) {    // A tile MTx64
            int s   = it * 256 + tid;
            int ln  = s & 63;
            int grp = s >> 6;
            int tile = grp >> 1, kst = grp & 1;
            int row = tile * 16 + (ln & 15);
            int kk  = kst * 32 + (ln >> 4) * 8;
            int ar = gm0 + row; if (ar >= M) ar = M - 1;
            gld_lds16(&A[(size_t)ar * lda + kc + kk],
                      &As[(it * 256 + wave * 64) * 8]);
        }
    };

    floatx4 acc[MI][4];
#pragma unroll
    for (int i = 0; i < MI; ++i)
#pragma unroll
        for (int j = 0; j < 4; ++j) acc[i][j] = (floatx4)(0.f);

    const int nk = K >> 6;
    stage(0, 0);
    __syncthreads();
    for (int t = 0; t < nk; ++t) {
        if (t + 1 < nk) stage((t + 1) * 64, (t + 1) & 1);
        const ushort_t* As = sbuf + (t & 1) * HALF;
        const ushort_t* Ws = As + MT * 64;
#pragma unroll
        for (int kst = 0; kst < 2; ++kst) {
            short8 af[MI], wf[4];
#pragma unroll
            for (int i = 0; i < MI; ++i) {
                int mt = mhalf * MI + i;
                af[i] = *(const short8*)&As[((mt * 2 + kst) * 64 + lane) * 8];
            }
#pragma unroll
            for (int j = 0; j < 4; ++j) {
                int ot = ohalf * 4 + j;
                wf[j] = *(const short8*)&Ws[((ot * 2 + kst) * 64 + lane) * 8];
            }
#pragma unroll
            for (int i = 0; i < MI; ++i)
#pragma unroll
                for (int j = 0; j < 4; ++j)
                    acc[i][j] = __builtin_amdgcn_mfma_f32_16x16x32_bf16(
                        af[i], wf[j], acc[i][j], 0, 0, 0);
        }
        __syncthreads();
    }

    // ---- epilogue ----
    ushort_t* B16 = sbuf;

    if (LN) {
#pragma unroll
        for (int j = 0; j < 4; ++j) {
            int oc = (ohalf * 4 + j) * 16 + (lane & 15);
            float bj = bias[oc];
#pragma unroll
            for (int i = 0; i < MI; ++i) {
                int rbase = gm0 + (mhalf * MI + i) * 16 + (lane >> 4) * 4;
#pragma unroll
                for (int r = 0; r < 4; ++r) {
                    int rowc = rbase + r; if (rowc >= M) rowc = M - 1;
                    float rv = resb ? bf2f(resb[(size_t)rowc * HID + oc])
                                    : resf[(size_t)rowc * HID + oc];
                    acc[i][j][r] += bj + rv;
                }
            }
        }
#pragma unroll
        for (int i = 0; i < MI; ++i) {
#pragma unroll
            for (int r = 0; r < 4; ++r) {
                float s1 = acc[i][0][r] + acc[i][1][r] + acc[i][2][r] + acc[i][3][r];
                float s2 = acc[i][0][r] * acc[i][0][r] + acc[i][1][r] * acc[i][1][r]
                         + acc[i][2][r] * acc[i][2][r] + acc[i][3][r] * acc[i][3][r];
                s1 += __shfl_xor(s1, 1); s1 += __shfl_xor(s1, 2);
                s1 += __shfl_xor(s1, 4); s1 += __shfl_xor(s1, 8);
                s2 += __shfl_xor(s2, 1); s2 += __shfl_xor(s2, 2);
                s2 += __shfl_xor(s2, 4); s2 += __shfl_xor(s2, 8);
                if ((lane & 15) == 0) {
                    int rl = (mhalf * MI + i) * 16 + (lane >> 4) * 4 + r;
                    pS[rl][ohalf] = s1;
                    pQ[rl][ohalf] = s2;
                }
            }
        }
        __syncthreads();
#pragma unroll
        for (int i = 0; i < MI; ++i) {
#pragma unroll
            for (int r = 0; r < 4; ++r) {
                int rl = (mhalf * MI + i) * 16 + (lane >> 4) * 4 + r;
                float S = pS[rl][0] + pS[rl][1];
                float Q = pQ[rl][0] + pQ[rl][1];
                float mu = S * (1.f / 128.f);
                float var = Q * (1.f / 128.f) - mu * mu;
                float rstd = rsqrtf(var + 1e-5f);
#pragma unroll
                for (int j = 0; j < 4; ++j) {
                    int oc = (ohalf * 4 + j) * 16 + (lane & 15);
                    acc[i][j][r] = (acc[i][j][r] - mu) * rstd * g[oc] + be[oc];
                }
            }
        }
        __syncthreads();
    }

#pragma unroll
    for (int i = 0; i < MI; ++i)
#pragma unroll
        for (int j = 0; j < 4; ++j) {
            int oc = (ohalf * 4 + j) * 16 + (lane & 15);
            float bj = LN ? 0.f : bias[o0 + oc];
#pragma unroll
            for (int r = 0; r < 4; ++r) {
                int rl = (mhalf * MI + i) * 16 + (lane >> 4) * 4 + r;
                float v = acc[i][j][r] + bj;
                if (ACT) v = gelu_f(v);
                B16[rl * 136 + oc] = f2bf(v);
            }
        }
    __syncthreads();
#pragma unroll
    for (int p = 0; p < MT / 16; ++p) {
        int row = p * 16 + (tid >> 4);
        int ch  = tid & 15;
        if (gm0 + row < M)
            *(short8*)&outb[(size_t)(gm0 + row) * ostride + o0 + ch * 8] =
                *(const short8*)&B16[row * 136 + ch * 8];
    }
    if (LN && hfragp) {
        // emit h-frag image: [tile16][4 kst][64 lane][8] (coalesced 1KB/wave)
        int kst = tid >> 6, ln = tid & 63;
#pragma unroll
        for (int p = 0; p < MT / 16; ++p) {
            if (gm0 + p * 16 < M) {
                int gt = (gm0 >> 4) + p;
                short8 v = *(const short8*)&B16[(p * 16 + (ln & 15)) * 136
                                                + kst * 32 + (ln >> 4) * 8];
                *(short8*)&hfragp[(((size_t)gt * 4 + kst) * 64 + ln) * 8] = v;
            }
        }
    }
}

// ---------------- FF1: wave-independent frag GEMM + GELU -> a1 fp8 image -----
__global__ __launch_bounds__(256)
void ff1w_kernel(const ushort_t* __restrict__ hfrag,
                 const ushort_t* __restrict__ w1frag,
                 const float* __restrict__ b1,
                 unsigned char* __restrict__ a1img, int M)
{
    __shared__ __align__(16) ushort_t sT[4][16 * 136];   // per-wave transpose buf
    const int wave = threadIdx.x >> 6, lane = threadIdx.x & 63;
    const int cg = wave;
    const int nt16 = (M + 15) / 16;
    const int gt0 = blockIdx.x * 2;
    const int gt1 = gt0 + 1;
    const int gt1c = (gt1 < nt16) ? gt1 : nt16 - 1;
    const int l15 = lane & 15, l4 = lane >> 4;

    floatx4 acc[2][8];
#pragma unroll
    for (int i = 0; i < 2; ++i)
#pragma unroll
        for (int j = 0; j < 8; ++j) acc[i][j] = (floatx4)(0.f);

#pragma unroll
    for (int kst = 0; kst < 4; ++kst) {
        short8 a0 = *(const short8*)&hfrag[(((size_t)gt0  * 4 + kst) * 64 + lane) * 8];
        short8 a1 = *(const short8*)&hfrag[(((size_t)gt1c * 4 + kst) * 64 + lane) * 8];
        short8 bv[8];
#pragma unroll
        for (int j = 0; j < 8; ++j)
            bv[j] = *(const short8*)&w1frag[((((size_t)cg * 8 + j) * 4 + kst) * 64 + lane) * 8];
#pragma unroll
        for (int j = 0; j < 8; ++j) {
            acc[0][j] = __builtin_amdgcn_mfma_f32_16x16x32_bf16(a0, bv[j], acc[0][j], 0, 0, 0);
            acc[1][j] = __builtin_amdgcn_mfma_f32_16x16x32_bf16(a1, bv[j], acc[1][j], 0, 0, 0);
        }
    }

    float b1v[8];
#pragma unroll
    for (int j = 0; j < 8; ++j) b1v[j] = b1[cg * 128 + j * 16 + l15];

#pragma unroll
    for (int i = 0; i < 2; ++i) {
        const int gt = i ? gt1 : gt0;
#pragma unroll
        for (int j = 0; j < 8; ++j)
#pragma unroll
            for (int r = 0; r < 4; ++r)
                sT[wave][(l4 * 4 + r) * 136 + j * 16 + l15] =
                    f2bf(gelu_f(acc[i][j][r] + b1v[j]));
        if (gt < nt16) {
#pragma unroll
            for (int q = 0; q < 4; ++q) {
                float v[8];
#pragma unroll
                for (int e = 0; e < 8; ++e)
                    v[e] = bf2f(sT[wave][l15 * 136 + q * 32 + l4 * 8 + e]) * A1_SCALE;
                unsigned u0 = 0, u1 = 0;
                u0 = __builtin_amdgcn_cvt_pk_fp8_f32(v[0], v[1], u0, false);
                u0 = __builtin_amdgcn_cvt_pk_fp8_f32(v[2], v[3], u0, true);
                u1 = __builtin_amdgcn_cvt_pk_fp8_f32(v[4], v[5], u1, false);
                u1 = __builtin_amdgcn_cvt_pk_fp8_f32(v[6], v[7], u1, true);
                uint2 o; o.x = u0; o.y = u1;
                *(uint2*)(a1img + (((size_t)gt * 16 + cg * 4 + q) * 64 + lane) * 8) = o;
            }
        }
    }
}

// ---------------- FF2: wave-independent fp8 frag GEMM + residual + LN2 -------
__global__ __launch_bounds__(256)
void ff2w_kernel(const unsigned char* __restrict__ a1img,
                 const unsigned char* __restrict__ w2frag8,
                 const ushort_t* __restrict__ hb,
                 const float* __restrict__ b2,
                 const float* __restrict__ g, const float* __restrict__ be,
                 float* __restrict__ out, int M)
{
    const int wave = threadIdx.x >> 6, lane = threadIdx.x & 63;
    const int t32 = blockIdx.x * 4 + wave;
    const int nt32 = (M + 31) / 32;
    if (t32 >= nt32) return;
    const int nt16 = (M + 15) / 16;
    const int gt0 = t32 * 2;
    const int gt1c = (gt0 + 1 < nt16) ? gt0 + 1 : nt16 - 1;
    const int l15 = lane & 15, l4 = lane >> 4;

    floatx4 acc[2][8];
#pragma unroll
    for (int i = 0; i < 2; ++i)
#pragma unroll
        for (int j = 0; j < 8; ++j) acc[i][j] = (floatx4)(0.f);

#pragma unroll
    for (int kst = 0; kst < 16; ++kst) {
        long a0 = *(const long*)(a1img + (((size_t)gt0  * 16 + kst) * 64 + lane) * 8);
        long a1 = *(const long*)(a1img + (((size_t)gt1c * 16 + kst) * 64 + lane) * 8);
        long bv[8];
#pragma unroll
        for (int j = 0; j < 8; ++j)
            bv[j] = *(const long*)(w2frag8 + (((size_t)j * 16 + kst) * 64 + lane) * 8);
#pragma unroll
        for (int j = 0; j < 8; ++j) {
            acc[0][j] = __builtin_amdgcn_mfma_f32_16x16x32_fp8_fp8(a0, bv[j], acc[0][j], 0, 0, 0);
            acc[1][j] = __builtin_amdgcn_mfma_f32_16x16x32_fp8_fp8(a1, bv[j], acc[1][j], 0, 0, 0);
        }
    }

    float b2v[8], gv[8], bev[8];
#pragma unroll
    for (int j = 0; j < 8; ++j) {
        int oc = j * 16 + l15;
        b2v[j] = b2[oc]; gv[j] = g[oc]; bev[j] = be[oc];
    }

#pragma unroll
    for (int i = 0; i < 2; ++i) {
        const int rb = (t32 * 2 + i) * 16;
#pragma unroll
        for (int j = 0; j < 8; ++j) {
            int oc = j * 16 + l15;
#pragma unroll
            for (int r = 0; r < 4; ++r) {
                int row = rb + l4 * 4 + r;
                int rc = (row < M) ? row : M - 1;
                acc[i][j][r] = acc[i][j][r] * FF2_DESCALE + b2v[j]
                             + bf2f(hb[(size_t)rc * HID + oc]);
            }
        }
#pragma unroll
        for (int r = 0; r < 4; ++r) {
            float s1 = 0.f, s2 = 0.f;
#pragma unroll
            for (int j = 0; j < 8; ++j) {
                s1 += acc[i][j][r];
                s2 += acc[i][j][r] * acc[i][j][r];
            }
            s1 += __shfl_xor(s1, 1); s1 += __shfl_xor(s1, 2);
            s1 += __shfl_xor(s1, 4); s1 += __shfl_xor(s1, 8);
            s2 += __shfl_xor(s2, 1); s2 += __shfl_xor(s2, 2);
            s2 += __shfl_xor(s2, 4); s2 += __shfl_xor(s2, 8);
            float mu = s1 * (1.f / 128.f);
            float var = s2 * (1.f / 128.f) - mu * mu;
            float rstd = rsqrtf(var + 1e-5f);
            int row = rb + l4 * 4 + r;
            if (row < M) {
#pragma unroll
                for (int j = 0; j < 8; ++j)
                    out[(size_t)row * HID + j * 16 + l15] =
                        (acc[i][j][r] - mu) * rstd * gv[j] + bev[j];
            }
        }
    }
}

// ---------------- counting-sort scan chain ----------------------------------
__global__ __launch_bounds__(256)
void scan1_kernel(const int* __restrict__ cnt, int* __restrict__ parts, int N)
{
    __shared__ int sd[256];
    int t = threadIdx.x;
    int base = blockIdx.x * 1024 + t * 4;
    int s = 0;
#pragma unroll
    for (int j = 0; j < 4; ++j) if (base + j < N) s += cnt[base + j];
    sd[t] = s; __syncthreads();
    for (int off = 128; off; off >>= 1) {
        if (t < off) sd[t] += sd[t + off];
        __syncthreads();
    }
    if (t == 0) parts[blockIdx.x] = sd[0];
}

__global__ __launch_bounds__(256)
void scan2_kernel(const int* __restrict__ parts, int* __restrict__ poff, int nb)
{
    __shared__ int sd[256];
    int t = threadIdx.x;
    int v = (t < nb) ? parts[t] : 0;
    sd[t] = v; __syncthreads();
    for (int off = 1; off < 256; off <<= 1) {
        int u = (t >= off) ? sd[t - off] : 0;
        __syncthreads();
        sd[t] += u;
        __syncthreads();
    }
    if (t < nb) poff[t] = sd[t] - v;   // exclusive
}

__global__ __launch_bounds__(256)
void scan3_kernel(const int* __restrict__ cnt, const int* __restrict__ poff,
                  int* __restrict__ rp, int N)
{
    __shared__ int sd[256];
    int t = threadIdx.x;
    int base = blockIdx.x * 1024 + t * 4;
    int v0 = (base + 0 < N) ? cnt[base + 0] : 0;
    int v1 = (base + 1 < N) ? cnt[base + 1] : 0;
    int v2 = (base + 2 < N) ? cnt[base + 2] : 0;
    int v3 = (base + 3 < N) ? cnt[base + 3] : 0;
    int s = v0 + v1 + v2 + v3;
    sd[t] = s; __syncthreads();
    for (int off = 1; off < 256; off <<= 1) {
        int u = (t >= off) ? sd[t - off] : 0;
        __syncthreads();
        sd[t] += u;
        __syncthreads();
    }
    int o = poff[blockIdx.x] + sd[t] - s;
    if (base + 0 < N) rp[base + 0] = o;
    if (base + 1 < N) rp[base + 1] = o + v0;
    if (base + 2 < N) rp[base + 2] = o + v0 + v1;
    if (base + 3 < N) rp[base + 3] = o + v0 + v1 + v2;
}

// cohort scatter: blockIdx.x & 7 keys the XCD; each cohort owns 1/8 of nodes.
__global__ __launch_bounds__(256)
void scatter_kernel(const int* __restrict__ src, const int* __restrict__ dst,
                    int* __restrict__ rp, int* __restrict__ ssrc, int E, int N)
{
    int coh = blockIdx.x & 7;
    int bc  = blockIdx.x >> 3;
    int rr  = (N + 7) >> 3;
    int nlo = coh * rr;
    int nhi = nlo + rr; if (nhi > N) nhi = N;
    int stride = (gridDim.x >> 3) * 256;
    for (int e = bc * 256 + threadIdx.x; e < E; e += stride) {
        int d = dst[e];
        if (d >= nlo && d < nhi) {
            int pos = atomicAdd(&rp[d], 1);
            ssrc[pos] = src[e];
        }
    }
}

// ---------------- fused attention: 4 edges per wave-step ---------------------
__global__ __launch_bounds__(256)
void attn_fused_kernel(const ushort_t* __restrict__ qkvb, const int* __restrict__ rp,
                       const int* __restrict__ ssrc, ushort_t* __restrict__ aggb, int N)
{
    int wave = threadIdx.x >> 6, lane = threadIdx.x & 63;
    int n = blockIdx.x * 4 + wave;
    if (n >= N) return;
    int grp = lane >> 4;            // 0..3 edge slot
    int cb  = (lane & 15) * 16;     // byte offset of this lane's 16B chunk
    const char* base = (const char*)qkvb;

    short8 qv = *(const short8*)(base + n * QKV_ROWB + cb);
    float q[8];
#pragma unroll
    for (int j = 0; j < 8; ++j) q[j] = bf2f((ushort_t)qv[j]) * (0.25f / KV_SCALE);

    int r0 = n ? rp[n - 1] : 0;
    int r1 = rp[n];
    float acc[8] = {0.f, 0.f, 0.f, 0.f, 0.f, 0.f, 0.f, 0.f};
    float l = 0.f;

    int r = r0;
    for (; r + 8 <= r1; r += 8) {
        int s0 = ssrc[r + grp];
        int s1 = ssrc[r + 4 + grp];
        uint4 kv0 = *(const uint4*)(base + s0 * QKV_ROWB + 256 + cb);
        uint4 kv1 = *(const uint4*)(base + s1 * QKV_ROWB + 256 + cb);

        f32x2 a0 = __builtin_amdgcn_cvt_pk_f32_fp8(kv0.x, false);
        f32x2 a1 = __builtin_amdgcn_cvt_pk_f32_fp8(kv0.x, true);
        f32x2 a2 = __builtin_amdgcn_cvt_pk_f32_fp8(kv0.y, false);
        f32x2 a3 = __builtin_amdgcn_cvt_pk_f32_fp8(kv0.y, true);
        f32x2 b0 = __builtin_amdgcn_cvt_pk_f32_fp8(kv1.x, false);
        f32x2 b1 = __builtin_amdgcn_cvt_pk_f32_fp8(kv1.x, true);
        f32x2 b2 = __builtin_amdgcn_cvt_pk_f32_fp8(kv1.y, false);
        f32x2 b3 = __builtin_amdgcn_cvt_pk_f32_fp8(kv1.y, true);

        float p0 = 0.f, p1 = 0.f;
        p0 = fmaf(q[0], a0.x, p0); p0 = fmaf(q[1], a0.y, p0);
        p0 = fmaf(q[2], a1.x, p0); p0 = fmaf(q[3], a1.y, p0);
        p0 = fmaf(q[4], a2.x, p0); p0 = fmaf(q[5], a2.y, p0);
        p0 = fmaf(q[6], a3.x, p0); p0 = fmaf(q[7], a3.y, p0);
        p1 = fmaf(q[0], b0.x, p1); p1 = fmaf(q[1], b0.y, p1);
        p1 = fmaf(q[2], b1.x, p1); p1 = fmaf(q[3], b1.y, p1);
        p1 = fmaf(q[4], b2.x, p1); p1 = fmaf(q[5], b2.y, p1);
        p1 = fmaf(q[6], b3.x, p1); p1 = fmaf(q[7], b3.y, p1);

        p0 += __shfl_xor(p0, 1);
        p1 += __shfl_xor(p1, 1);
        float e0 = __expf(p0), e1 = __expf(p1);
        l += e0 + e1;

        f32x2 v0 = __builtin_amdgcn_cvt_pk_f32_fp8(kv0.z, false);
        f32x2 v1 = __builtin_amdgcn_cvt_pk_f32_fp8(kv0.z, true);
        f32x2 v2 = __builtin_amdgcn_cvt_pk_f32_fp8(kv0.w, false);
        f32x2 v3 = __builtin_amdgcn_cvt_pk_f32_fp8(kv0.w, true);
        f32x2 w0 = __builtin_amdgcn_cvt_pk_f32_fp8(kv1.z, false);
        f32x2 w1 = __builtin_amdgcn_cvt_pk_f32_fp8(kv1.z, true);
        f32x2 w2 = __builtin_amdgcn_cvt_pk_f32_fp8(kv1.w, false);
        f32x2 w3 = __builtin_amdgcn_cvt_pk_f32_fp8(kv1.w, true);

        acc[0] = fmaf(e0, v0.x, acc[0]); acc[1] = fmaf(e0, v0.y, acc[1]);
        acc[2] = fmaf(e0, v1.x, acc[2]); acc[3] = fmaf(e0, v1.y, acc[3]);
        acc[4] = fmaf(e0, v2.x, acc[4]); acc[5] = fmaf(e0, v2.y, acc[5]);
        acc[6] = fmaf(e0, v3.x, acc[6]); acc[7] = fmaf(e0, v3.y, acc[7]);
        acc[0] = fmaf(e1, w0.x, acc[0]); acc[1] = fmaf(e1, w0.y, acc[1]);
        acc[2] = fmaf(e1, w1.x, acc[2]); acc[3] = fmaf(e1, w1.y, acc[3]);
        acc[4] = fmaf(e1, w2.x, acc[4]); acc[5] = fmaf(e1, w2.y, acc[5]);
        acc[6] = fmaf(e1, w3.x, acc[6]); acc[7] = fmaf(e1, w3.y, acc[7]);
    }
    for (; r < r1; r += 4) {
        int e = r + grp;
        int s = ssrc[(e < r1) ? e : r0];
        uint4 kv = *(const uint4*)(base + s * QKV_ROWB + 256 + cb);
        f32x2 a0 = __builtin_amdgcn_cvt_pk_f32_fp8(kv.x, false);
        f32x2 a1 = __builtin_amdgcn_cvt_pk_f32_fp8(kv.x, true);
        f32x2 a2 = __builtin_amdgcn_cvt_pk_f32_fp8(kv.y, false);
        f32x2 a3 = __builtin_amdgcn_cvt_pk_f32_fp8(kv.y, true);
        float p = 0.f;
        p = fmaf(q[0], a0.x, p); p = fmaf(q[1], a0.y, p);
        p = fmaf(q[2], a1.x, p); p = fmaf(q[3], a1.y, p);
        p = fmaf(q[4], a2.x, p); p = fmaf(q[5], a2.y, p);
        p = fmaf(q[6], a3.x, p); p = fmaf(q[7], a3.y, p);
        p += __shfl_xor(p, 1);
        float ea = (e < r1) ? __expf(p) : 0.f;
        l += ea;
        f32x2 v0 = __builtin_amdgcn_cvt_pk_f32_fp8(kv.z, false);
        f32x2 v1 = __builtin_amdgcn_cvt_pk_f32_fp8(kv.z, true);
        f32x2 v2 = __builtin_amdgcn_cvt_pk_f32_fp8(kv.w, false);
        f32x2 v3 = __builtin_amdgcn_cvt_pk_f32_fp8(kv.w, true);
        acc[0] = fmaf(ea, v0.x, acc[0]); acc[1] = fmaf(ea, v0.y, acc[1]);
        acc[2] = fmaf(ea, v1.x, acc[2]); acc[3] = fmaf(ea, v1.y, acc[3]);
        acc[4] = fmaf(ea, v2.x, acc[4]); acc[5] = fmaf(ea, v2.y, acc[5]);
        acc[6] = fmaf(ea, v3.x, acc[6]); acc[7] = fmaf(ea, v3.y, acc[7]);
    }

#pragma unroll
    for (int j = 0; j < 8; ++j) {
        acc[j] += __shfl_xor(acc[j], 16);
        acc[j] += __shfl_xor(acc[j], 32);
    }
    l += __shfl_xor(l, 16);
    l += __shfl_xor(l, 32);
    float inv = KV_INV_SCALE / (l + 1e-16f);
    if (grp == 0) {
        short8 o;
#pragma unroll
        for (int j = 0; j < 8; ++j) o[j] = (short)f2bf(acc[j] * inv);
        *(short8*)((char*)aggb + n * 256 + cb) = o;
    }
}

// ============================================================================
extern "C" void kernel_launch(void* const* d_in, const int* in_sizes, int n_in,
                              void* d_out, int out_size, void* d_ws, size_t ws_size,
                              hipStream_t stream)
{
    const float* x  = (const float*)d_in[0];
    const int*   ei = (const int*)d_in[1];
    const float* Wq = (const float*)d_in[2];
    const float* bq = (const float*)d_in[3];
    const float* Wk = (const float*)d_in[4];
    const float* bk = (const float*)d_in[5];
    const float* Wv = (const float*)d_in[6];
    const float* bv = (const float*)d_in[7];
    const float* Wo = (const float*)d_in[8];
    const float* bo = (const float*)d_in[9];
    const float* W1 = (const float*)d_in[10];
    const float* b1 = (const float*)d_in[11];
    const float* W2 = (const float*)d_in[12];
    const float* b2 = (const float*)d_in[13];
    const float* g1 = (const float*)d_in[14];
    const float* be1= (const float*)d_in[15];
    const float* g2 = (const float*)d_in[16];
    const float* be2= (const float*)d_in[17];
    float* out = (float*)d_out;

    const int N = in_sizes[0] / HID;      // 50000
    const int E = in_sizes[1] / 2;        // 800000
    const int* srcp = ei;
    const int* dstp = ei + E;

    const size_t NH = (size_t)N * HID;    // 6.4M
    float* wsf = (float*)d_ws;

    const int nt16 = (N + 15) / 16;       // 3125
    const int nt32 = (N + 31) / 32;       // 1563

    // ---- workspace layout (f32 units) ----
    ushort_t* xfrag = (ushort_t*)wsf;                 // [0, 0.5NH)  dies after QKV
    ushort_t* qkvb  = (ushort_t*)(wsf + NH / 2);      // [0.5, 1.5)  dies after attn
    ushort_t* hfrag = (ushort_t*)(wsf + NH + NH / 2); // [1.5, 2.0)  h frag image
    ushort_t* aggb  = (ushort_t*)(wsf + 2 * NH);      // [2.0, 2.5)  dies after Wo
    ushort_t* hb    = (ushort_t*)wsf;                 // [0, 0.5)    overlays dead xfrag
    unsigned char* a1img = (unsigned char*)(wsf + NH / 2); // [0.5,1.5) overlays dead qkvb

    ushort_t* U       = (ushort_t*)(wsf + 2 * NH + NH / 2);
    ushort_t* woB     = U;                              // 16384 ushort
    ushort_t* wqkvf   = U + 16384;                      // 49152 ushort
    ushort_t* w1frag  = U + 65536;                      // 65536 ushort
    unsigned char* w2frag8 = (unsigned char*)(U + 131072); // 65536 B
    float*    bqkv = (float*)(w2frag8 + 65536);         // 384 f32
    int*      rp   = (int*)(bqkv + 384);                // N+1
    int*      cnt  = rp + (N + 1);                      // N
    int*      poff = cnt + N;                           // 256
    int*      parts= poff + 256;                        // 256
    int*      ssrc = parts + 256;                       // E

    // ---- prep (streaming only; counting moved to cohort kernel) ----
    hipMemsetAsync(cnt, 0, N * sizeof(int), stream);
    const int xchunks = nt16 * 256;       // 800000
    const int ptot = xchunks + 8192 + 6144 + 8192 + 8192 + 384;
    prep_kernel<<<(ptot + 255) / 256, 256, 0, stream>>>(
        x, Wq, Wk, Wv, Wo, W1, W2, bq, bk, bv,
        xfrag, woB, wqkvf, w1frag, w2frag8, bqkv, xchunks);

    // ---- cohort degree count + counting sort of edges by dst ----
    count_kernel<<<2048, 256, 0, stream>>>(dstp, cnt, E, N);
    const int nb = (N + 1023) / 1024;   // 49
    scan1_kernel<<<nb, 256, 0, stream>>>(cnt, parts, N);
    scan2_kernel<<<1, 256, 0, stream>>>(parts, poff, nb);
    scan3_kernel<<<nb, 256, 0, stream>>>(cnt, poff, rp, N);
    scatter_kernel<<<2048, 256, 0, stream>>>(srcp, dstp, rp, ssrc, E, N);

    // ---- QKV (wave-independent frag GEMM): y=0 q bf16, y=1/2 k/v fp8 ----
    qkvw_kernel<<<dim3((nt16 + 7) / 8, 3), 256, 0, stream>>>(
        xfrag, wqkvf, bqkv, qkvb, nt16);

    // ---- fused attention ----
    attn_fused_kernel<<<(N + 3) / 4, 256, 0, stream>>>(qkvb, rp, ssrc, aggb, N);

    // ---- Wo + residual(x) + LN1 -> hb (bf16) + hfrag (frag image) ----
    const int gx64 = (N + 63) / 64;     // 782
    gemm_t<64, 0, 1, 0><<<dim3(gx64, 1), 256, 0, stream>>>(
        aggb, HID, N, woB, HID, bo, hfrag, hb, HID,
        x, nullptr, g1, be1);

    // ---- FF1 (frag images, wave-independent) -> a1 fp8 image ----
    ff1w_kernel<<<nt32, 256, 0, stream>>>(hfrag, w1frag, b1, a1img, N);

    // ---- FF2 (fp8 frag GEMM) + residual(hb) + LN2 -> out (f32) ----
    ff2w_kernel<<<(nt32 + 3) / 4, 256, 0, stream>>>(
        a1img, w2frag8, hb, b2, g2, be2, out, N);
}

// Round 9
// 321.060 us; speedup vs baseline: 1.3575x; 1.0042x over previous
//
#include <hip/hip_runtime.h>
#include <math.h>

#define N_HEADS 8
#define HEAD_DIM 16
#define HID 128
// qkv row: 256B q (bf16) + 16 x [8B k fp8 | 8B v fp8] = 512B
#define QKV_ROWB 512

typedef unsigned short ushort_t;
typedef __attribute__((ext_vector_type(8))) short short8;
typedef __attribute__((ext_vector_type(4))) float floatx4;
typedef __attribute__((ext_vector_type(2))) float f32x2;

#define KV_SCALE 64.0f
#define KV_INV_SCALE 0.015625f

// FF fp8 scales: W2 x 2^16, a1 x 2^9
#define W2_SCALE 65536.0f
#define A1_SCALE 512.0f
#define FF2_DESCALE (1.0f / 33554432.0f)   // 1/(512*65536)

__device__ __forceinline__ ushort_t f2bf(float f) {
    unsigned u = __float_as_uint(f);
    unsigned r = (u + 0x7FFFu + ((u >> 16) & 1u)) >> 16;
    return (ushort_t)r;
}
__device__ __forceinline__ float bf2f(ushort_t u) {
    return __uint_as_float(((unsigned)u) << 16);
}

// fast exact-GELU: erf via Abramowitz-Stegun 7.1.26 (|err| <= 1.5e-7)
__device__ __forceinline__ float gelu_f(float x) {
    float z = fabsf(x) * 0.70710678118654752f;
    float t = 1.0f / (1.0f + 0.3275911f * z);
    float y = t * (0.254829592f + t * (-0.284496736f + t * (1.421413741f
            + t * (-1.453152027f + t * 1.061405429f))));
    float e = 1.0f - y * __expf(-z * z);
    e = copysignf(e, x);
    return 0.5f * x * (1.0f + e);
}

// ---- prep: x frag, Wo frag, Wq/Wk/Wv frag, W1 frag, W2 fp8 frag, bias -------
// frag layout (16x16x32 MFMA A/B): [tile16][kst][lane][8]; elem =
// (row = t16*16 + (lane&15), k = kst*32 + (lane>>4)*8 + e). One wave frag
// load at runtime is a single coalesced 512B/1KB segment.
__global__ __launch_bounds__(256)
void prep_kernel(const float* __restrict__ x,
                 const float* __restrict__ Wq, const float* __restrict__ Wk,
                 const float* __restrict__ Wv, const float* __restrict__ Wo,
                 const float* __restrict__ W1, const float* __restrict__ W2,
                 const float* __restrict__ bq, const float* __restrict__ bk,
                 const float* __restrict__ bv,
                 ushort_t* __restrict__ xfrag, ushort_t* __restrict__ wofrag,
                 ushort_t* __restrict__ wqkvf,
                 ushort_t* __restrict__ w1frag,
                 unsigned char* __restrict__ w2frag8,
                 float* __restrict__ bqkv, int xchunks)
{
    int i = blockIdx.x * 256 + threadIdx.x;
    if (i < xchunks) {                      // x -> frag image (8 f32 -> 8 bf16)
        int t16 = i >> 8;
        int rem = i & 255;
        int lane = rem & 63;
        int row = t16 * 16 + (lane & 15);
        int k   = (rem >> 6) * 32 + (lane >> 4) * 8;
        const float* s = x + (size_t)row * HID + k;
        short8 v;
#pragma unroll
        for (int e = 0; e < 8; ++e) v[e] = (short)f2bf(s[e]);
        *(short8*)(xfrag + (size_t)i * 8) = v;
        return;
    }
    int j = i - xchunks;
    if (j < 2048) {                         // Wo-frag bf16: [8 t16][4 kst][64][8]
        int lane = j & 63, tk = j >> 6;
        int t16 = tk >> 2, kst = tk & 3;
        int row = t16 * 16 + (lane & 15);
        int kb  = kst * 32 + (lane >> 4) * 8;
        const float* s = Wo + (size_t)row * HID + kb;
        short8 v;
#pragma unroll
        for (int e = 0; e < 8; ++e) v[e] = (short)f2bf(s[e]);
        *(short8*)(wofrag + (size_t)j * 8) = v;
        return;
    }
    int b = j - 2048;
    if (b < 6144) {                         // Wq/Wk/Wv frag: 3 x [8][4][64][8]
        int w = b >> 11;
        int rem = b & 2047;
        int t16 = rem >> 8;
        int rem2 = rem & 255;
        int lane = rem2 & 63;
        int row = t16 * 16 + (lane & 15);
        int k   = ((rem2 >> 6) & 3) * 32 + (lane >> 4) * 8;
        const float* W = (w == 0) ? Wq : (w == 1) ? Wk : Wv;
        const float* s = W + (size_t)row * HID + k;
        short8 v;
#pragma unroll
        for (int e = 0; e < 8; ++e) v[e] = (short)f2bf(s[e]);
        *(short8*)(wqkvf + (size_t)b * 8) = v;
        return;
    }
    int c = b - 6144;
    if (c < 8192) {                         // W1-frag bf16: [32 t16][4 kst][64][8]
        int lane = c & 63, tk = c >> 6;
        int t16 = tk >> 2, kst = tk & 3;
        int row = t16 * 16 + (lane & 15);
        int kb  = kst * 32 + (lane >> 4) * 8;
        const float* s = W1 + (size_t)row * HID + kb;
        short8 v;
#pragma unroll
        for (int e = 0; e < 8; ++e) v[e] = (short)f2bf(s[e]);
        *(short8*)(w1frag + (size_t)c * 8) = v;
        return;
    }
    int c2 = c - 8192;
    if (c2 < 8192) {                        // W2-frag fp8 x2^16: [8 t16][16 kst][64][8]
        int lane = c2 & 63, tk = c2 >> 6;
        int t16 = tk >> 4, kst = tk & 15;
        int row = t16 * 16 + (lane & 15);
        int kb  = kst * 32 + (lane >> 4) * 8;
        const float* s = W2 + (size_t)row * 512 + kb;
        unsigned u0 = 0, u1 = 0;
        u0 = __builtin_amdgcn_cvt_pk_fp8_f32(s[0]*W2_SCALE, s[1]*W2_SCALE, u0, false);
        u0 = __builtin_amdgcn_cvt_pk_fp8_f32(s[2]*W2_SCALE, s[3]*W2_SCALE, u0, true);
        u1 = __builtin_amdgcn_cvt_pk_fp8_f32(s[4]*W2_SCALE, s[5]*W2_SCALE, u1, false);
        u1 = __builtin_amdgcn_cvt_pk_fp8_f32(s[6]*W2_SCALE, s[7]*W2_SCALE, u1, true);
        uint2 o; o.x = u0; o.y = u1;
        *(uint2*)(w2frag8 + (size_t)c2 * 8) = o;
        return;
    }
    int d = c2 - 8192;
    if (d < 384) {
        bqkv[d] = (d < 128) ? bq[d] : (d < 256) ? bk[d - 128] : bv[d - 256];
    }
}

// cohort degree count: blockIdx.x & 7 keys the XCD; each cohort counts only
// its 1/8 node range -> cnt lines stay within ONE L2 (mirrors scatter fix).
__global__ __launch_bounds__(256)
void count_kernel(const int* __restrict__ dst, int* __restrict__ cnt, int E, int N)
{
    int coh = blockIdx.x & 7;
    int bc  = blockIdx.x >> 3;
    int rr  = (N + 7) >> 3;
    int nlo = coh * rr;
    int nhi = nlo + rr; if (nhi > N) nhi = N;
    int stride = (gridDim.x >> 3) * 256;
    for (int e = bc * 256 + threadIdx.x; e < E; e += stride) {
        int d = dst[e];
        if (d >= nlo && d < nhi) atomicAdd(&cnt[d], 1);
    }
}

// ---------------- QKV: wave-independent frag GEMM ----------------------------
__global__ __launch_bounds__(256)
void qkvw_kernel(const ushort_t* __restrict__ xfrag,
                 const ushort_t* __restrict__ wqkvf,
                 const float* __restrict__ bqkv,
                 ushort_t* __restrict__ qkvb, int nt16)
{
    __shared__ __align__(16) ushort_t sT[4][16 * 136];
    const int wave = threadIdx.x >> 6, lane = threadIdx.x & 63;
    const int y = blockIdx.y;
    const int l15 = lane & 15, l4 = lane >> 4;
    const int gt0 = blockIdx.x * 8 + wave * 2;
    const int gt0c = (gt0 < nt16) ? gt0 : nt16 - 1;
    const int gt1c = (gt0 + 1 < nt16) ? gt0 + 1 : nt16 - 1;

    floatx4 acc[2][8];
#pragma unroll
    for (int i = 0; i < 2; ++i)
#pragma unroll
        for (int j = 0; j < 8; ++j) acc[i][j] = (floatx4)(0.f);

    const ushort_t* wf = wqkvf + (size_t)y * 16384;
#pragma unroll
    for (int kst = 0; kst < 4; ++kst) {
        short8 a0 = *(const short8*)&xfrag[(((size_t)gt0c * 4 + kst) * 64 + lane) * 8];
        short8 a1 = *(const short8*)&xfrag[(((size_t)gt1c * 4 + kst) * 64 + lane) * 8];
        short8 bv[8];
#pragma unroll
        for (int j = 0; j < 8; ++j)
            bv[j] = *(const short8*)&wf[(((size_t)j * 4 + kst) * 64 + lane) * 8];
#pragma unroll
        for (int j = 0; j < 8; ++j) {
            acc[0][j] = __builtin_amdgcn_mfma_f32_16x16x32_bf16(a0, bv[j], acc[0][j], 0, 0, 0);
            acc[1][j] = __builtin_amdgcn_mfma_f32_16x16x32_bf16(a1, bv[j], acc[1][j], 0, 0, 0);
        }
    }

    float bb[8];
#pragma unroll
    for (int j = 0; j < 8; ++j) bb[j] = bqkv[y * 128 + j * 16 + l15];

#pragma unroll
    for (int i = 0; i < 2; ++i) {
        const int gt = gt0 + i;
#pragma unroll
        for (int j = 0; j < 8; ++j)
#pragma unroll
            for (int r = 0; r < 4; ++r) {
                float v = acc[i][j][r] + bb[j];
                if (y) v *= KV_SCALE;
                sT[wave][(l4 * 4 + r) * 136 + j * 16 + l15] = f2bf(v);
            }
        if (gt < nt16) {
            if (y == 0) {
#pragma unroll
                for (int c = 0; c < 4; ++c) {
                    int ch = l4 * 4 + c;
                    *(short8*)&qkvb[(size_t)(gt * 16 + l15) * 256 + ch * 8] =
                        *(const short8*)&sT[wave][l15 * 136 + ch * 8];
                }
            } else {
                const int koff = (y - 1) * 8;
#pragma unroll
                for (int c = 0; c < 4; ++c) {
                    int ch = l4 * 4 + c;
                    short8 s = *(const short8*)&sT[wave][l15 * 136 + ch * 8];
                    unsigned u0 = 0, u1 = 0;
                    u0 = __builtin_amdgcn_cvt_pk_fp8_f32(
                             bf2f((ushort_t)s[0]), bf2f((ushort_t)s[1]), u0, false);
                    u0 = __builtin_amdgcn_cvt_pk_fp8_f32(
                             bf2f((ushort_t)s[2]), bf2f((ushort_t)s[3]), u0, true);
                    u1 = __builtin_amdgcn_cvt_pk_fp8_f32(
                             bf2f((ushort_t)s[4]), bf2f((ushort_t)s[5]), u1, false);
                    u1 = __builtin_amdgcn_cvt_pk_fp8_f32(
                             bf2f((ushort_t)s[6]), bf2f((ushort_t)s[7]), u1, true);
                    uint2 o; o.x = u0; o.y = u1;
                    *(uint2*)((char*)qkvb + (size_t)(gt * 16 + l15) * QKV_ROWB
                              + 256 + ch * 16 + koff) = o;
                }
            }
        }
    }
}

// ---------------- Wo: wave-independent frag GEMM + residual(x) + LN1 ---------
// Wave owns rows [t32*32, +32). Inputs: aggfrag (attn emits frag layout),
// wofrag. Outputs: hb row-major bf16 + hfrag image. MFMA k-order identical to
// the old gemm_t path (k chunks ascending 0,32,64,96) -> bit-identical h.
__global__ __launch_bounds__(256)
void wow_kernel(const ushort_t* __restrict__ aggfrag,
                const ushort_t* __restrict__ wofrag,
                const float* __restrict__ bo,
                const float* __restrict__ x,
                const float* __restrict__ g, const float* __restrict__ be,
                ushort_t* __restrict__ hb, ushort_t* __restrict__ hfrag, int M)
{
    __shared__ __align__(16) ushort_t sT[4][16 * 136];
    const int wave = threadIdx.x >> 6, lane = threadIdx.x & 63;
    const int t32 = blockIdx.x * 4 + wave;
    const int nt32 = (M + 31) / 32;
    if (t32 >= nt32) return;
    const int nt16 = (M + 15) / 16;
    const int gt0 = t32 * 2;
    const int gt1c = (gt0 + 1 < nt16) ? gt0 + 1 : nt16 - 1;
    const int l15 = lane & 15, l4 = lane >> 4;

    floatx4 acc[2][8];
#pragma unroll
    for (int i = 0; i < 2; ++i)
#pragma unroll
        for (int j = 0; j < 8; ++j) acc[i][j] = (floatx4)(0.f);

#pragma unroll
    for (int kst = 0; kst < 4; ++kst) {
        short8 a0 = *(const short8*)&aggfrag[(((size_t)gt0  * 4 + kst) * 64 + lane) * 8];
        short8 a1 = *(const short8*)&aggfrag[(((size_t)gt1c * 4 + kst) * 64 + lane) * 8];
        short8 bv[8];
#pragma unroll
        for (int j = 0; j < 8; ++j)
            bv[j] = *(const short8*)&wofrag[(((size_t)j * 4 + kst) * 64 + lane) * 8];
#pragma unroll
        for (int j = 0; j < 8; ++j) {
            acc[0][j] = __builtin_amdgcn_mfma_f32_16x16x32_bf16(a0, bv[j], acc[0][j], 0, 0, 0);
            acc[1][j] = __builtin_amdgcn_mfma_f32_16x16x32_bf16(a1, bv[j], acc[1][j], 0, 0, 0);
        }
    }

    float bov[8], gv[8], bev[8];
#pragma unroll
    for (int j = 0; j < 8; ++j) {
        int oc = j * 16 + l15;
        bov[j] = bo[oc]; gv[j] = g[oc]; bev[j] = be[oc];
    }

#pragma unroll
    for (int i = 0; i < 2; ++i) {
        const int gt = gt0 + i;
        const int rb = gt * 16;
#pragma unroll
        for (int j = 0; j < 8; ++j) {
            int oc = j * 16 + l15;
#pragma unroll
            for (int r = 0; r < 4; ++r) {
                int row = rb + l4 * 4 + r;
                int rc = (row < M) ? row : M - 1;
                acc[i][j][r] += bov[j] + x[(size_t)rc * HID + oc];
            }
        }
#pragma unroll
        for (int r = 0; r < 4; ++r) {
            float s1 = 0.f, s2 = 0.f;
#pragma unroll
            for (int j = 0; j < 8; ++j) {
                s1 += acc[i][j][r];
                s2 += acc[i][j][r] * acc[i][j][r];
            }
            s1 += __shfl_xor(s1, 1); s1 += __shfl_xor(s1, 2);
            s1 += __shfl_xor(s1, 4); s1 += __shfl_xor(s1, 8);
            s2 += __shfl_xor(s2, 1); s2 += __shfl_xor(s2, 2);
            s2 += __shfl_xor(s2, 4); s2 += __shfl_xor(s2, 8);
            float mu = s1 * (1.f / 128.f);
            float var = s2 * (1.f / 128.f) - mu * mu;
            float rstd = rsqrtf(var + 1e-5f);
#pragma unroll
            for (int j = 0; j < 8; ++j) {
                float v = (acc[i][j][r] - mu) * rstd * gv[j] + bev[j];
                sT[wave][(l4 * 4 + r) * 136 + j * 16 + l15] = f2bf(v);
            }
        }
        if (gt < nt16) {
#pragma unroll
            for (int c = 0; c < 4; ++c) {
                int ch = l4 * 4 + c;
                *(short8*)&hb[(size_t)(gt * 16 + l15) * HID + ch * 8] =
                    *(const short8*)&sT[wave][l15 * 136 + ch * 8];
            }
#pragma unroll
            for (int q = 0; q < 4; ++q)
                *(short8*)&hfrag[(((size_t)gt * 4 + q) * 64 + lane) * 8] =
                    *(const short8*)&sT[wave][l15 * 136 + q * 32 + l4 * 8];
        }
    }
}

// ---------------- FF1: wave-independent frag GEMM + GELU -> a1 fp8 image -----
__global__ __launch_bounds__(256)
void ff1w_kernel(const ushort_t* __restrict__ hfrag,
                 const ushort_t* __restrict__ w1frag,
                 const float* __restrict__ b1,
                 unsigned char* __restrict__ a1img, int M)
{
    __shared__ __align__(16) ushort_t sT[4][16 * 136];   // per-wave transpose buf
    const int wave = threadIdx.x >> 6, lane = threadIdx.x & 63;
    const int cg = wave;
    const int nt16 = (M + 15) / 16;
    const int gt0 = blockIdx.x * 2;
    const int gt1 = gt0 + 1;
    const int gt1c = (gt1 < nt16) ? gt1 : nt16 - 1;
    const int l15 = lane & 15, l4 = lane >> 4;

    floatx4 acc[2][8];
#pragma unroll
    for (int i = 0; i < 2; ++i)
#pragma unroll
        for (int j = 0; j < 8; ++j) acc[i][j] = (floatx4)(0.f);

#pragma unroll
    for (int kst = 0; kst < 4; ++kst) {
        short8 a0 = *(const short8*)&hfrag[(((size_t)gt0  * 4 + kst) * 64 + lane) * 8];
        short8 a1 = *(const short8*)&hfrag[(((size_t)gt1c * 4 + kst) * 64 + lane) * 8];
        short8 bv[8];
#pragma unroll
        for (int j = 0; j < 8; ++j)
            bv[j] = *(const short8*)&w1frag[((((size_t)cg * 8 + j) * 4 + kst) * 64 + lane) * 8];
#pragma unroll
        for (int j = 0; j < 8; ++j) {
            acc[0][j] = __builtin_amdgcn_mfma_f32_16x16x32_bf16(a0, bv[j], acc[0][j], 0, 0, 0);
            acc[1][j] = __builtin_amdgcn_mfma_f32_16x16x32_bf16(a1, bv[j], acc[1][j], 0, 0, 0);
        }
    }

    float b1v[8];
#pragma unroll
    for (int j = 0; j < 8; ++j) b1v[j] = b1[cg * 128 + j * 16 + l15];

#pragma unroll
    for (int i = 0; i < 2; ++i) {
        const int gt = i ? gt1 : gt0;
#pragma unroll
        for (int j = 0; j < 8; ++j)
#pragma unroll
            for (int r = 0; r < 4; ++r)
                sT[wave][(l4 * 4 + r) * 136 + j * 16 + l15] =
                    f2bf(gelu_f(acc[i][j][r] + b1v[j]));
        if (gt < nt16) {
#pragma unroll
            for (int q = 0; q < 4; ++q) {
                float v[8];
#pragma unroll
                for (int e = 0; e < 8; ++e)
                    v[e] = bf2f(sT[wave][l15 * 136 + q * 32 + l4 * 8 + e]) * A1_SCALE;
                unsigned u0 = 0, u1 = 0;
                u0 = __builtin_amdgcn_cvt_pk_fp8_f32(v[0], v[1], u0, false);
                u0 = __builtin_amdgcn_cvt_pk_fp8_f32(v[2], v[3], u0, true);
                u1 = __builtin_amdgcn_cvt_pk_fp8_f32(v[4], v[5], u1, false);
                u1 = __builtin_amdgcn_cvt_pk_fp8_f32(v[6], v[7], u1, true);
                uint2 o; o.x = u0; o.y = u1;
                *(uint2*)(a1img + (((size_t)gt * 16 + cg * 4 + q) * 64 + lane) * 8) = o;
            }
        }
    }
}

// ---------------- FF2: wave-independent fp8 frag GEMM + residual + LN2 -------
__global__ __launch_bounds__(256)
void ff2w_kernel(const unsigned char* __restrict__ a1img,
                 const unsigned char* __restrict__ w2frag8,
                 const ushort_t* __restrict__ hb,
                 const float* __restrict__ b2,
                 const float* __restrict__ g, const float* __restrict__ be,
                 float* __restrict__ out, int M)
{
    const int wave = threadIdx.x >> 6, lane = threadIdx.x & 63;
    const int t32 = blockIdx.x * 4 + wave;
    const int nt32 = (M + 31) / 32;
    if (t32 >= nt32) return;
    const int nt16 = (M + 15) / 16;
    const int gt0 = t32 * 2;
    const int gt1c = (gt0 + 1 < nt16) ? gt0 + 1 : nt16 - 1;
    const int l15 = lane & 15, l4 = lane >> 4;

    floatx4 acc[2][8];
#pragma unroll
    for (int i = 0; i < 2; ++i)
#pragma unroll
        for (int j = 0; j < 8; ++j) acc[i][j] = (floatx4)(0.f);

#pragma unroll
    for (int kst = 0; kst < 16; ++kst) {
        long a0 = *(const long*)(a1img + (((size_t)gt0  * 16 + kst) * 64 + lane) * 8);
        long a1 = *(const long*)(a1img + (((size_t)gt1c * 16 + kst) * 64 + lane) * 8);
        long bv[8];
#pragma unroll
        for (int j = 0; j < 8; ++j)
            bv[j] = *(const long*)(w2frag8 + (((size_t)j * 16 + kst) * 64 + lane) * 8);
#pragma unroll
        for (int j = 0; j < 8; ++j) {
            acc[0][j] = __builtin_amdgcn_mfma_f32_16x16x32_fp8_fp8(a0, bv[j], acc[0][j], 0, 0, 0);
            acc[1][j] = __builtin_amdgcn_mfma_f32_16x16x32_fp8_fp8(a1, bv[j], acc[1][j], 0, 0, 0);
        }
    }

    float b2v[8], gv[8], bev[8];
#pragma unroll
    for (int j = 0; j < 8; ++j) {
        int oc = j * 16 + l15;
        b2v[j] = b2[oc]; gv[j] = g[oc]; bev[j] = be[oc];
    }

#pragma unroll
    for (int i = 0; i < 2; ++i) {
        const int rb = (t32 * 2 + i) * 16;
#pragma unroll
        for (int j = 0; j < 8; ++j) {
            int oc = j * 16 + l15;
#pragma unroll
            for (int r = 0; r < 4; ++r) {
                int row = rb + l4 * 4 + r;
                int rc = (row < M) ? row : M - 1;
                acc[i][j][r] = acc[i][j][r] * FF2_DESCALE + b2v[j]
                             + bf2f(hb[(size_t)rc * HID + oc]);
            }
        }
#pragma unroll
        for (int r = 0; r < 4; ++r) {
            float s1 = 0.f, s2 = 0.f;
#pragma unroll
            for (int j = 0; j < 8; ++j) {
                s1 += acc[i][j][r];
                s2 += acc[i][j][r] * acc[i][j][r];
            }
            s1 += __shfl_xor(s1, 1); s1 += __shfl_xor(s1, 2);
            s1 += __shfl_xor(s1, 4); s1 += __shfl_xor(s1, 8);
            s2 += __shfl_xor(s2, 1); s2 += __shfl_xor(s2, 2);
            s2 += __shfl_xor(s2, 4); s2 += __shfl_xor(s2, 8);
            float mu = s1 * (1.f / 128.f);
            float var = s2 * (1.f / 128.f) - mu * mu;
            float rstd = rsqrtf(var + 1e-5f);
            int row = rb + l4 * 4 + r;
            if (row < M) {
#pragma unroll
                for (int j = 0; j < 8; ++j)
                    out[(size_t)row * HID + j * 16 + l15] =
                        (acc[i][j][r] - mu) * rstd * gv[j] + bev[j];
            }
        }
    }
}

// ---------------- counting-sort scan chain ----------------------------------
__global__ __launch_bounds__(256)
void scan1_kernel(const int* __restrict__ cnt, int* __restrict__ parts, int N)
{
    __shared__ int sd[256];
    int t = threadIdx.x;
    int base = blockIdx.x * 1024 + t * 4;
    int s = 0;
#pragma unroll
    for (int j = 0; j < 4; ++j) if (base + j < N) s += cnt[base + j];
    sd[t] = s; __syncthreads();
    for (int off = 128; off; off >>= 1) {
        if (t < off) sd[t] += sd[t + off];
        __syncthreads();
    }
    if (t == 0) parts[blockIdx.x] = sd[0];
}

__global__ __launch_bounds__(256)
void scan2_kernel(const int* __restrict__ parts, int* __restrict__ poff, int nb)
{
    __shared__ int sd[256];
    int t = threadIdx.x;
    int v = (t < nb) ? parts[t] : 0;
    sd[t] = v; __syncthreads();
    for (int off = 1; off < 256; off <<= 1) {
        int u = (t >= off) ? sd[t - off] : 0;
        __syncthreads();
        sd[t] += u;
        __syncthreads();
    }
    if (t < nb) poff[t] = sd[t] - v;   // exclusive
}

__global__ __launch_bounds__(256)
void scan3_kernel(const int* __restrict__ cnt, const int* __restrict__ poff,
                  int* __restrict__ rp, int N)
{
    __shared__ int sd[256];
    int t = threadIdx.x;
    int base = blockIdx.x * 1024 + t * 4;
    int v0 = (base + 0 < N) ? cnt[base + 0] : 0;
    int v1 = (base + 1 < N) ? cnt[base + 1] : 0;
    int v2 = (base + 2 < N) ? cnt[base + 2] : 0;
    int v3 = (base + 3 < N) ? cnt[base + 3] : 0;
    int s = v0 + v1 + v2 + v3;
    sd[t] = s; __syncthreads();
    for (int off = 1; off < 256; off <<= 1) {
        int u = (t >= off) ? sd[t - off] : 0;
        __syncthreads();
        sd[t] += u;
        __syncthreads();
    }
    int o = poff[blockIdx.x] + sd[t] - s;
    if (base + 0 < N) rp[base + 0] = o;
    if (base + 1 < N) rp[base + 1] = o + v0;
    if (base + 2 < N) rp[base + 2] = o + v0 + v1;
    if (base + 3 < N) rp[base + 3] = o + v0 + v1 + v2;
}

// cohort scatter: blockIdx.x & 7 keys the XCD; each cohort owns 1/8 of nodes.
__global__ __launch_bounds__(256)
void scatter_kernel(const int* __restrict__ src, const int* __restrict__ dst,
                    int* __restrict__ rp, int* __restrict__ ssrc, int E, int N)
{
    int coh = blockIdx.x & 7;
    int bc  = blockIdx.x >> 3;
    int rr  = (N + 7) >> 3;
    int nlo = coh * rr;
    int nhi = nlo + rr; if (nhi > N) nhi = N;
    int stride = (gridDim.x >> 3) * 256;
    for (int e = bc * 256 + threadIdx.x; e < E; e += stride) {
        int d = dst[e];
        if (d >= nlo && d < nhi) {
            int pos = atomicAdd(&rp[d], 1);
            ssrc[pos] = src[e];
        }
    }
}

// ---------------- fused attention: 4 edges per wave-step ---------------------
// Output now written directly in MFMA frag-image layout (consumed by wow):
// grp-0 lane L holds node n channels [8L, 8L+8) -> kst=L>>2, lane'=(n&15)+16*(L&3).
__global__ __launch_bounds__(256)
void attn_fused_kernel(const ushort_t* __restrict__ qkvb, const int* __restrict__ rp,
                       const int* __restrict__ ssrc, ushort_t* __restrict__ aggfrag, int N)
{
    int wave = threadIdx.x >> 6, lane = threadIdx.x & 63;
    int n = blockIdx.x * 4 + wave;
    if (n >= N) return;
    int grp = lane >> 4;            // 0..3 edge slot
    int cb  = (lane & 15) * 16;     // byte offset of this lane's 16B chunk
    const char* base = (const char*)qkvb;

    short8 qv = *(const short8*)(base + n * QKV_ROWB + cb);
    float q[8];
#pragma unroll
    for (int j = 0; j < 8; ++j) q[j] = bf2f((ushort_t)qv[j]) * (0.25f / KV_SCALE);

    int r0 = n ? rp[n - 1] : 0;
    int r1 = rp[n];
    float acc[8] = {0.f, 0.f, 0.f, 0.f, 0.f, 0.f, 0.f, 0.f};
    float l = 0.f;

    int r = r0;
    for (; r + 8 <= r1; r += 8) {
        int s0 = ssrc[r + grp];
        int s1 = ssrc[r + 4 + grp];
        uint4 kv0 = *(const uint4*)(base + s0 * QKV_ROWB + 256 + cb);
        uint4 kv1 = *(const uint4*)(base + s1 * QKV_ROWB + 256 + cb);

        f32x2 a0 = __builtin_amdgcn_cvt_pk_f32_fp8(kv0.x, false);
        f32x2 a1 = __builtin_amdgcn_cvt_pk_f32_fp8(kv0.x, true);
        f32x2 a2 = __builtin_amdgcn_cvt_pk_f32_fp8(kv0.y, false);
        f32x2 a3 = __builtin_amdgcn_cvt_pk_f32_fp8(kv0.y, true);
        f32x2 b0 = __builtin_amdgcn_cvt_pk_f32_fp8(kv1.x, false);
        f32x2 b1 = __builtin_amdgcn_cvt_pk_f32_fp8(kv1.x, true);
        f32x2 b2 = __builtin_amdgcn_cvt_pk_f32_fp8(kv1.y, false);
        f32x2 b3 = __builtin_amdgcn_cvt_pk_f32_fp8(kv1.y, true);

        float p0 = 0.f, p1 = 0.f;
        p0 = fmaf(q[0], a0.x, p0); p0 = fmaf(q[1], a0.y, p0);
        p0 = fmaf(q[2], a1.x, p0); p0 = fmaf(q[3], a1.y, p0);
        p0 = fmaf(q[4], a2.x, p0); p0 = fmaf(q[5], a2.y, p0);
        p0 = fmaf(q[6], a3.x, p0); p0 = fmaf(q[7], a3.y, p0);
        p1 = fmaf(q[0], b0.x, p1); p1 = fmaf(q[1], b0.y, p1);
        p1 = fmaf(q[2], b1.x, p1); p1 = fmaf(q[3], b1.y, p1);
        p1 = fmaf(q[4], b2.x, p1); p1 = fmaf(q[5], b2.y, p1);
        p1 = fmaf(q[6], b3.x, p1); p1 = fmaf(q[7], b3.y, p1);

        p0 += __shfl_xor(p0, 1);
        p1 += __shfl_xor(p1, 1);
        float e0 = __expf(p0), e1 = __expf(p1);
        l += e0 + e1;

        f32x2 v0 = __builtin_amdgcn_cvt_pk_f32_fp8(kv0.z, false);
        f32x2 v1 = __builtin_amdgcn_cvt_pk_f32_fp8(kv0.z, true);
        f32x2 v2 = __builtin_amdgcn_cvt_pk_f32_fp8(kv0.w, false);
        f32x2 v3 = __builtin_amdgcn_cvt_pk_f32_fp8(kv0.w, true);
        f32x2 w0 = __builtin_amdgcn_cvt_pk_f32_fp8(kv1.z, false);
        f32x2 w1 = __builtin_amdgcn_cvt_pk_f32_fp8(kv1.z, true);
        f32x2 w2 = __builtin_amdgcn_cvt_pk_f32_fp8(kv1.w, false);
        f32x2 w3 = __builtin_amdgcn_cvt_pk_f32_fp8(kv1.w, true);

        acc[0] = fmaf(e0, v0.x, acc[0]); acc[1] = fmaf(e0, v0.y, acc[1]);
        acc[2] = fmaf(e0, v1.x, acc[2]); acc[3] = fmaf(e0, v1.y, acc[3]);
        acc[4] = fmaf(e0, v2.x, acc[4]); acc[5] = fmaf(e0, v2.y, acc[5]);
        acc[6] = fmaf(e0, v3.x, acc[6]); acc[7] = fmaf(e0, v3.y, acc[7]);
        acc[0] = fmaf(e1, w0.x, acc[0]); acc[1] = fmaf(e1, w0.y, acc[1]);
        acc[2] = fmaf(e1, w1.x, acc[2]); acc[3] = fmaf(e1, w1.y, acc[3]);
        acc[4] = fmaf(e1, w2.x, acc[4]); acc[5] = fmaf(e1, w2.y, acc[5]);
        acc[6] = fmaf(e1, w3.x, acc[6]); acc[7] = fmaf(e1, w3.y, acc[7]);
    }
    for (; r < r1; r += 4) {
        int e = r + grp;
        int s = ssrc[(e < r1) ? e : r0];
        uint4 kv = *(const uint4*)(base + s * QKV_ROWB + 256 + cb);
        f32x2 a0 = __builtin_amdgcn_cvt_pk_f32_fp8(kv.x, false);
        f32x2 a1 = __builtin_amdgcn_cvt_pk_f32_fp8(kv.x, true);
        f32x2 a2 = __builtin_amdgcn_cvt_pk_f32_fp8(kv.y, false);
        f32x2 a3 = __builtin_amdgcn_cvt_pk_f32_fp8(kv.y, true);
        float p = 0.f;
        p = fmaf(q[0], a0.x, p); p = fmaf(q[1], a0.y, p);
        p = fmaf(q[2], a1.x, p); p = fmaf(q[3], a1.y, p);
        p = fmaf(q[4], a2.x, p); p = fmaf(q[5], a2.y, p);
        p = fmaf(q[6], a3.x, p); p = fmaf(q[7], a3.y, p);
        p += __shfl_xor(p, 1);
        float ea = (e < r1) ? __expf(p) : 0.f;
        l += ea;
        f32x2 v0 = __builtin_amdgcn_cvt_pk_f32_fp8(kv.z, false);
        f32x2 v1 = __builtin_amdgcn_cvt_pk_f32_fp8(kv.z, true);
        f32x2 v2 = __builtin_amdgcn_cvt_pk_f32_fp8(kv.w, false);
        f32x2 v3 = __builtin_amdgcn_cvt_pk_f32_fp8(kv.w, true);
        acc[0] = fmaf(ea, v0.x, acc[0]); acc[1] = fmaf(ea, v0.y, acc[1]);
        acc[2] = fmaf(ea, v1.x, acc[2]); acc[3] = fmaf(ea, v1.y, acc[3]);
        acc[4] = fmaf(ea, v2.x, acc[4]); acc[5] = fmaf(ea, v2.y, acc[5]);
        acc[6] = fmaf(ea, v3.x, acc[6]); acc[7] = fmaf(ea, v3.y, acc[7]);
    }

#pragma unroll
    for (int j = 0; j < 8; ++j) {
        acc[j] += __shfl_xor(acc[j], 16);
        acc[j] += __shfl_xor(acc[j], 32);
    }
    l += __shfl_xor(l, 16);
    l += __shfl_xor(l, 32);
    float inv = KV_INV_SCALE / (l + 1e-16f);
    if (grp == 0) {
        short8 o;
#pragma unroll
        for (int j = 0; j < 8; ++j) o[j] = (short)f2bf(acc[j] * inv);
        int t16 = n >> 4, kst = lane >> 2;
        int lp = (n & 15) + ((lane & 3) << 4);
        *(short8*)&aggfrag[(((size_t)t16 * 4 + kst) * 64 + lp) * 8] = o;
    }
}

// ============================================================================
extern "C" void kernel_launch(void* const* d_in, const int* in_sizes, int n_in,
                              void* d_out, int out_size, void* d_ws, size_t ws_size,
                              hipStream_t stream)
{
    const float* x  = (const float*)d_in[0];
    const int*   ei = (const int*)d_in[1];
    const float* Wq = (const float*)d_in[2];
    const float* bq = (const float*)d_in[3];
    const float* Wk = (const float*)d_in[4];
    const float* bk = (const float*)d_in[5];
    const float* Wv = (const float*)d_in[6];
    const float* bv = (const float*)d_in[7];
    const float* Wo = (const float*)d_in[8];
    const float* bo = (const float*)d_in[9];
    const float* W1 = (const float*)d_in[10];
    const float* b1 = (const float*)d_in[11];
    const float* W2 = (const float*)d_in[12];
    const float* b2 = (const float*)d_in[13];
    const float* g1 = (const float*)d_in[14];
    const float* be1= (const float*)d_in[15];
    const float* g2 = (const float*)d_in[16];
    const float* be2= (const float*)d_in[17];
    float* out = (float*)d_out;

    const int N = in_sizes[0] / HID;      // 50000
    const int E = in_sizes[1] / 2;        // 800000
    const int* srcp = ei;
    const int* dstp = ei + E;

    const size_t NH = (size_t)N * HID;    // 6.4M
    float* wsf = (float*)d_ws;

    const int nt16 = (N + 15) / 16;       // 3125
    const int nt32 = (N + 31) / 32;       // 1563

    // ---- workspace layout (f32 units) ----
    ushort_t* xfrag   = (ushort_t*)wsf;                 // [0, 0.5NH)  dies after QKV
    ushort_t* qkvb    = (ushort_t*)(wsf + NH / 2);      // [0.5, 1.5)  dies after attn
    ushort_t* hfrag   = (ushort_t*)(wsf + NH + NH / 2); // [1.5, 2.0)  h frag image
    ushort_t* aggfrag = (ushort_t*)(wsf + 2 * NH);      // [2.0, 2.5)  dies after Wo
    ushort_t* hb      = (ushort_t*)wsf;                 // [0, 0.5)    overlays dead xfrag
    unsigned char* a1img = (unsigned char*)(wsf + NH / 2); // [0.5,1.5) overlays dead qkvb

    ushort_t* U       = (ushort_t*)(wsf + 2 * NH + NH / 2);
    ushort_t* wofrag  = U;                              // 16384 ushort
    ushort_t* wqkvf   = U + 16384;                      // 49152 ushort
    ushort_t* w1frag  = U + 65536;                      // 65536 ushort
    unsigned char* w2frag8 = (unsigned char*)(U + 131072); // 65536 B
    float*    bqkv = (float*)(w2frag8 + 65536);         // 384 f32
    int*      rp   = (int*)(bqkv + 384);                // N+1
    int*      cnt  = rp + (N + 1);                      // N
    int*      poff = cnt + N;                           // 256
    int*      parts= poff + 256;                        // 256
    int*      ssrc = parts + 256;                       // E

    // ---- prep (streaming only) ----
    hipMemsetAsync(cnt, 0, N * sizeof(int), stream);
    const int xchunks = nt16 * 256;       // 800000
    const int ptot = xchunks + 2048 + 6144 + 8192 + 8192 + 384;
    prep_kernel<<<(ptot + 255) / 256, 256, 0, stream>>>(
        x, Wq, Wk, Wv, Wo, W1, W2, bq, bk, bv,
        xfrag, wofrag, wqkvf, w1frag, w2frag8, bqkv, xchunks);

    // ---- cohort degree count + counting sort of edges by dst ----
    count_kernel<<<2048, 256, 0, stream>>>(dstp, cnt, E, N);
    const int nb = (N + 1023) / 1024;   // 49
    scan1_kernel<<<nb, 256, 0, stream>>>(cnt, parts, N);
    scan2_kernel<<<1, 256, 0, stream>>>(parts, poff, nb);
    scan3_kernel<<<nb, 256, 0, stream>>>(cnt, poff, rp, N);
    scatter_kernel<<<2048, 256, 0, stream>>>(srcp, dstp, rp, ssrc, E, N);

    // ---- QKV (wave-independent frag GEMM): y=0 q bf16, y=1/2 k/v fp8 ----
    qkvw_kernel<<<dim3((nt16 + 7) / 8, 3), 256, 0, stream>>>(
        xfrag, wqkvf, bqkv, qkvb, nt16);

    // ---- fused attention (emits aggfrag in frag-image layout) ----
    attn_fused_kernel<<<(N + 3) / 4, 256, 0, stream>>>(qkvb, rp, ssrc, aggfrag, N);

    // ---- Wo (wave-independent frag GEMM) + residual(x) + LN1 -> hb + hfrag ----
    wow_kernel<<<(nt32 + 3) / 4, 256, 0, stream>>>(
        aggfrag, wofrag, bo, x, g1, be1, hb, hfrag, N);

    // ---- FF1 (frag images, wave-independent) -> a1 fp8 image ----
    ff1w_kernel<<<nt32, 256, 0, stream>>>(hfrag, w1frag, b1, a1img, N);

    // ---- FF2 (fp8 frag GEMM) + residual(hb) + LN2 -> out (f32) ----
    ff2w_kernel<<<(nt32 + 3) / 4, 256, 0, stream>>>(
        a1img, w2frag8, hb, b2, g2, be2, out, N);
}

// Round 10
// 295.814 us; speedup vs baseline: 1.4734x; 1.0853x over previous
//
#include <hip/hip_runtime.h>
#include <math.h>

#define N_HEADS 8
#define HEAD_DIM 16
#define HID 128
// qkv row: 256B q (bf16) + 16 x [8B k fp8 | 8B v fp8] = 512B
#define QKV_ROWB 512

typedef unsigned short ushort_t;
typedef __attribute__((ext_vector_type(8))) short short8;
typedef __attribute__((ext_vector_type(4))) float floatx4;
typedef __attribute__((ext_vector_type(2))) float f32x2;

#define KV_SCALE 64.0f
#define KV_INV_SCALE 0.015625f

// FF fp8 scales: W2 x 2^16, a1 x 2^9
#define W2_SCALE 65536.0f
#define A1_SCALE 512.0f
#define FF2_DESCALE (1.0f / 33554432.0f)   // 1/(512*65536)

__device__ __forceinline__ ushort_t f2bf(float f) {
    unsigned u = __float_as_uint(f);
    unsigned r = (u + 0x7FFFu + ((u >> 16) & 1u)) >> 16;
    return (ushort_t)r;
}
__device__ __forceinline__ float bf2f(ushort_t u) {
    return __uint_as_float(((unsigned)u) << 16);
}

// fast exact-GELU: erf via Abramowitz-Stegun 7.1.26 (|err| <= 1.5e-7)
__device__ __forceinline__ float gelu_f(float x) {
    float z = fabsf(x) * 0.70710678118654752f;
    float t = 1.0f / (1.0f + 0.3275911f * z);
    float y = t * (0.254829592f + t * (-0.284496736f + t * (1.421413741f
            + t * (-1.453152027f + t * 1.061405429f))));
    float e = 1.0f - y * __expf(-z * z);
    e = copysignf(e, x);
    return 0.5f * x * (1.0f + e);
}

// ---- prep: x frag, Wo frag, Wq/Wk/Wv frag, W1 frag, W2 fp8 frag, bias -------
// frag layout (16x16x32 MFMA A/B): [tile16][kst][lane][8]; elem =
// (row = t16*16 + (lane&15), k = kst*32 + (lane>>4)*8 + e). One wave frag
// load at runtime is a single coalesced 512B/1KB segment.
__global__ __launch_bounds__(256)
void prep_kernel(const float* __restrict__ x,
                 const float* __restrict__ Wq, const float* __restrict__ Wk,
                 const float* __restrict__ Wv, const float* __restrict__ Wo,
                 const float* __restrict__ W1, const float* __restrict__ W2,
                 const float* __restrict__ bq, const float* __restrict__ bk,
                 const float* __restrict__ bv,
                 ushort_t* __restrict__ xfrag, ushort_t* __restrict__ wofrag,
                 ushort_t* __restrict__ wqkvf,
                 ushort_t* __restrict__ w1frag,
                 unsigned char* __restrict__ w2frag8,
                 float* __restrict__ bqkv, int xchunks)
{
    int i = blockIdx.x * 256 + threadIdx.x;
    if (i < xchunks) {                      // x -> frag image (8 f32 -> 8 bf16)
        int t16 = i >> 8;
        int rem = i & 255;
        int lane = rem & 63;
        int row = t16 * 16 + (lane & 15);
        int k   = (rem >> 6) * 32 + (lane >> 4) * 8;
        const float* s = x + (size_t)row * HID + k;
        short8 v;
#pragma unroll
        for (int e = 0; e < 8; ++e) v[e] = (short)f2bf(s[e]);
        *(short8*)(xfrag + (size_t)i * 8) = v;
        return;
    }
    int j = i - xchunks;
    if (j < 2048) {                         // Wo-frag bf16: [8 t16][4 kst][64][8]
        int lane = j & 63, tk = j >> 6;
        int t16 = tk >> 2, kst = tk & 3;
        int row = t16 * 16 + (lane & 15);
        int kb  = kst * 32 + (lane >> 4) * 8;
        const float* s = Wo + (size_t)row * HID + kb;
        short8 v;
#pragma unroll
        for (int e = 0; e < 8; ++e) v[e] = (short)f2bf(s[e]);
        *(short8*)(wofrag + (size_t)j * 8) = v;
        return;
    }
    int b = j - 2048;
    if (b < 6144) {                         // Wq/Wk/Wv frag: 3 x [8][4][64][8]
        int w = b >> 11;
        int rem = b & 2047;
        int t16 = rem >> 8;
        int rem2 = rem & 255;
        int lane = rem2 & 63;
        int row = t16 * 16 + (lane & 15);
        int k   = ((rem2 >> 6) & 3) * 32 + (lane >> 4) * 8;
        const float* W = (w == 0) ? Wq : (w == 1) ? Wk : Wv;
        const float* s = W + (size_t)row * HID + k;
        short8 v;
#pragma unroll
        for (int e = 0; e < 8; ++e) v[e] = (short)f2bf(s[e]);
        *(short8*)(wqkvf + (size_t)b * 8) = v;
        return;
    }
    int c = b - 6144;
    if (c < 8192) {                         // W1-frag bf16: [32 t16][4 kst][64][8]
        int lane = c & 63, tk = c >> 6;
        int t16 = tk >> 2, kst = tk & 3;
        int row = t16 * 16 + (lane & 15);
        int kb  = kst * 32 + (lane >> 4) * 8;
        const float* s = W1 + (size_t)row * HID + kb;
        short8 v;
#pragma unroll
        for (int e = 0; e < 8; ++e) v[e] = (short)f2bf(s[e]);
        *(short8*)(w1frag + (size_t)c * 8) = v;
        return;
    }
    int c2 = c - 8192;
    if (c2 < 8192) {                        // W2-frag fp8 x2^16: [8 t16][16 kst][64][8]
        int lane = c2 & 63, tk = c2 >> 6;
        int t16 = tk >> 4, kst = tk & 15;
        int row = t16 * 16 + (lane & 15);
        int kb  = kst * 32 + (lane >> 4) * 8;
        const float* s = W2 + (size_t)row * 512 + kb;
        unsigned u0 = 0, u1 = 0;
        u0 = __builtin_amdgcn_cvt_pk_fp8_f32(s[0]*W2_SCALE, s[1]*W2_SCALE, u0, false);
        u0 = __builtin_amdgcn_cvt_pk_fp8_f32(s[2]*W2_SCALE, s[3]*W2_SCALE, u0, true);
        u1 = __builtin_amdgcn_cvt_pk_fp8_f32(s[4]*W2_SCALE, s[5]*W2_SCALE, u1, false);
        u1 = __builtin_amdgcn_cvt_pk_fp8_f32(s[6]*W2_SCALE, s[7]*W2_SCALE, u1, true);
        uint2 o; o.x = u0; o.y = u1;
        *(uint2*)(w2frag8 + (size_t)c2 * 8) = o;
        return;
    }
    int d = c2 - 8192;
    if (d < 384) {
        bqkv[d] = (d < 128) ? bq[d] : (d < 256) ? bk[d - 128] : bv[d - 256];
    }
}

// cohort degree count + per-edge rank: blockIdx.x & 7 keys the XCD; each
// cohort counts only its 1/8 node range (cnt lines stay in ONE L2). The
// returned old value is this edge's rank within its dst segment -> the
// scatter pass needs NO atomics (halves total atomic ops).
__global__ __launch_bounds__(256)
void count_kernel(const int* __restrict__ dst, int* __restrict__ cnt,
                  int* __restrict__ rank, int E, int N)
{
    int coh = blockIdx.x & 7;
    int bc  = blockIdx.x >> 3;
    int rr  = (N + 7) >> 3;
    int nlo = coh * rr;
    int nhi = nlo + rr; if (nhi > N) nhi = N;
    int stride = (gridDim.x >> 3) * 256;
    for (int e = bc * 256 + threadIdx.x; e < E; e += stride) {
        int d = dst[e];
        if (d >= nlo && d < nhi) rank[e] = atomicAdd(&cnt[d], 1);
    }
}

// ---------------- QKV: wave-independent frag GEMM ----------------------------
__global__ __launch_bounds__(256)
void qkvw_kernel(const ushort_t* __restrict__ xfrag,
                 const ushort_t* __restrict__ wqkvf,
                 const float* __restrict__ bqkv,
                 ushort_t* __restrict__ qkvb, int nt16)
{
    __shared__ __align__(16) ushort_t sT[4][16 * 136];
    const int wave = threadIdx.x >> 6, lane = threadIdx.x & 63;
    const int y = blockIdx.y;
    const int l15 = lane & 15, l4 = lane >> 4;
    const int gt0 = blockIdx.x * 8 + wave * 2;
    const int gt0c = (gt0 < nt16) ? gt0 : nt16 - 1;
    const int gt1c = (gt0 + 1 < nt16) ? gt0 + 1 : nt16 - 1;

    floatx4 acc[2][8];
#pragma unroll
    for (int i = 0; i < 2; ++i)
#pragma unroll
        for (int j = 0; j < 8; ++j) acc[i][j] = (floatx4)(0.f);

    const ushort_t* wf = wqkvf + (size_t)y * 16384;
#pragma unroll
    for (int kst = 0; kst < 4; ++kst) {
        short8 a0 = *(const short8*)&xfrag[(((size_t)gt0c * 4 + kst) * 64 + lane) * 8];
        short8 a1 = *(const short8*)&xfrag[(((size_t)gt1c * 4 + kst) * 64 + lane) * 8];
        short8 bv[8];
#pragma unroll
        for (int j = 0; j < 8; ++j)
            bv[j] = *(const short8*)&wf[(((size_t)j * 4 + kst) * 64 + lane) * 8];
#pragma unroll
        for (int j = 0; j < 8; ++j) {
            acc[0][j] = __builtin_amdgcn_mfma_f32_16x16x32_bf16(a0, bv[j], acc[0][j], 0, 0, 0);
            acc[1][j] = __builtin_amdgcn_mfma_f32_16x16x32_bf16(a1, bv[j], acc[1][j], 0, 0, 0);
        }
    }

    float bb[8];
#pragma unroll
    for (int j = 0; j < 8; ++j) bb[j] = bqkv[y * 128 + j * 16 + l15];

#pragma unroll
    for (int i = 0; i < 2; ++i) {
        const int gt = gt0 + i;
#pragma unroll
        for (int j = 0; j < 8; ++j)
#pragma unroll
            for (int r = 0; r < 4; ++r) {
                float v = acc[i][j][r] + bb[j];
                if (y) v *= KV_SCALE;
                sT[wave][(l4 * 4 + r) * 136 + j * 16 + l15] = f2bf(v);
            }
        if (gt < nt16) {
            if (y == 0) {
#pragma unroll
                for (int c = 0; c < 4; ++c) {
                    int ch = l4 * 4 + c;
                    *(short8*)&qkvb[(size_t)(gt * 16 + l15) * 256 + ch * 8] =
                        *(const short8*)&sT[wave][l15 * 136 + ch * 8];
                }
            } else {
                const int koff = (blockIdx.y - 1) * 8;
#pragma unroll
                for (int c = 0; c < 4; ++c) {
                    int ch = l4 * 4 + c;
                    short8 s = *(const short8*)&sT[wave][l15 * 136 + ch * 8];
                    unsigned u0 = 0, u1 = 0;
                    u0 = __builtin_amdgcn_cvt_pk_fp8_f32(
                             bf2f((ushort_t)s[0]), bf2f((ushort_t)s[1]), u0, false);
                    u0 = __builtin_amdgcn_cvt_pk_fp8_f32(
                             bf2f((ushort_t)s[2]), bf2f((ushort_t)s[3]), u0, true);
                    u1 = __builtin_amdgcn_cvt_pk_fp8_f32(
                             bf2f((ushort_t)s[4]), bf2f((ushort_t)s[5]), u1, false);
                    u1 = __builtin_amdgcn_cvt_pk_fp8_f32(
                             bf2f((ushort_t)s[6]), bf2f((ushort_t)s[7]), u1, true);
                    uint2 o; o.x = u0; o.y = u1;
                    *(uint2*)((char*)qkvb + (size_t)(gt * 16 + l15) * QKV_ROWB
                              + 256 + ch * 16 + koff) = o;
                }
            }
        }
    }
}

// ---------------- Wo: wave-independent frag GEMM + residual(x) + LN1 ---------
__global__ __launch_bounds__(256)
void wow_kernel(const ushort_t* __restrict__ aggfrag,
                const ushort_t* __restrict__ wofrag,
                const float* __restrict__ bo,
                const float* __restrict__ x,
                const float* __restrict__ g, const float* __restrict__ be,
                ushort_t* __restrict__ hb, ushort_t* __restrict__ hfrag, int M)
{
    __shared__ __align__(16) ushort_t sT[4][16 * 136];
    const int wave = threadIdx.x >> 6, lane = threadIdx.x & 63;
    const int t32 = blockIdx.x * 4 + wave;
    const int nt32 = (M + 31) / 32;
    if (t32 >= nt32) return;
    const int nt16 = (M + 15) / 16;
    const int gt0 = t32 * 2;
    const int gt1c = (gt0 + 1 < nt16) ? gt0 + 1 : nt16 - 1;
    const int l15 = lane & 15, l4 = lane >> 4;

    floatx4 acc[2][8];
#pragma unroll
    for (int i = 0; i < 2; ++i)
#pragma unroll
        for (int j = 0; j < 8; ++j) acc[i][j] = (floatx4)(0.f);

#pragma unroll
    for (int kst = 0; kst < 4; ++kst) {
        short8 a0 = *(const short8*)&aggfrag[(((size_t)gt0  * 4 + kst) * 64 + lane) * 8];
        short8 a1 = *(const short8*)&aggfrag[(((size_t)gt1c * 4 + kst) * 64 + lane) * 8];
        short8 bv[8];
#pragma unroll
        for (int j = 0; j < 8; ++j)
            bv[j] = *(const short8*)&wofrag[(((size_t)j * 4 + kst) * 64 + lane) * 8];
#pragma unroll
        for (int j = 0; j < 8; ++j) {
            acc[0][j] = __builtin_amdgcn_mfma_f32_16x16x32_bf16(a0, bv[j], acc[0][j], 0, 0, 0);
            acc[1][j] = __builtin_amdgcn_mfma_f32_16x16x32_bf16(a1, bv[j], acc[1][j], 0, 0, 0);
        }
    }

    float bov[8], gv[8], bev[8];
#pragma unroll
    for (int j = 0; j < 8; ++j) {
        int oc = j * 16 + l15;
        bov[j] = bo[oc]; gv[j] = g[oc]; bev[j] = be[oc];
    }

#pragma unroll
    for (int i = 0; i < 2; ++i) {
        const int gt = gt0 + i;
        const int rb = gt * 16;
#pragma unroll
        for (int j = 0; j < 8; ++j) {
            int oc = j * 16 + l15;
#pragma unroll
            for (int r = 0; r < 4; ++r) {
                int row = rb + l4 * 4 + r;
                int rc = (row < M) ? row : M - 1;
                acc[i][j][r] += bov[j] + x[(size_t)rc * HID + oc];
            }
        }
#pragma unroll
        for (int r = 0; r < 4; ++r) {
            float s1 = 0.f, s2 = 0.f;
#pragma unroll
            for (int j = 0; j < 8; ++j) {
                s1 += acc[i][j][r];
                s2 += acc[i][j][r] * acc[i][j][r];
            }
            s1 += __shfl_xor(s1, 1); s1 += __shfl_xor(s1, 2);
            s1 += __shfl_xor(s1, 4); s1 += __shfl_xor(s1, 8);
            s2 += __shfl_xor(s2, 1); s2 += __shfl_xor(s2, 2);
            s2 += __shfl_xor(s2, 4); s2 += __shfl_xor(s2, 8);
            float mu = s1 * (1.f / 128.f);
            float var = s2 * (1.f / 128.f) - mu * mu;
            float rstd = rsqrtf(var + 1e-5f);
#pragma unroll
            for (int j = 0; j < 8; ++j) {
                float v = (acc[i][j][r] - mu) * rstd * gv[j] + bev[j];
                sT[wave][(l4 * 4 + r) * 136 + j * 16 + l15] = f2bf(v);
            }
        }
        if (gt < nt16) {
#pragma unroll
            for (int c = 0; c < 4; ++c) {
                int ch = l4 * 4 + c;
                *(short8*)&hb[(size_t)(gt * 16 + l15) * HID + ch * 8] =
                    *(const short8*)&sT[wave][l15 * 136 + ch * 8];
            }
#pragma unroll
            for (int q = 0; q < 4; ++q)
                *(short8*)&hfrag[(((size_t)gt * 4 + q) * 64 + lane) * 8] =
                    *(const short8*)&sT[wave][l15 * 136 + q * 32 + l4 * 8];
        }
    }
}

// ---------------- FF1: wave-independent frag GEMM + GELU -> a1 fp8 image -----
__global__ __launch_bounds__(256)
void ff1w_kernel(const ushort_t* __restrict__ hfrag,
                 const ushort_t* __restrict__ w1frag,
                 const float* __restrict__ b1,
                 unsigned char* __restrict__ a1img, int M)
{
    __shared__ __align__(16) ushort_t sT[4][16 * 136];   // per-wave transpose buf
    const int wave = threadIdx.x >> 6, lane = threadIdx.x & 63;
    const int cg = wave;
    const int nt16 = (M + 15) / 16;
    const int gt0 = blockIdx.x * 2;
    const int gt1 = gt0 + 1;
    const int gt1c = (gt1 < nt16) ? gt1 : nt16 - 1;
    const int l15 = lane & 15, l4 = lane >> 4;

    floatx4 acc[2][8];
#pragma unroll
    for (int i = 0; i < 2; ++i)
#pragma unroll
        for (int j = 0; j < 8; ++j) acc[i][j] = (floatx4)(0.f);

#pragma unroll
    for (int kst = 0; kst < 4; ++kst) {
        short8 a0 = *(const short8*)&hfrag[(((size_t)gt0  * 4 + kst) * 64 + lane) * 8];
        short8 a1 = *(const short8*)&hfrag[(((size_t)gt1c * 4 + kst) * 64 + lane) * 8];
        short8 bv[8];
#pragma unroll
        for (int j = 0; j < 8; ++j)
            bv[j] = *(const short8*)&w1frag[((((size_t)cg * 8 + j) * 4 + kst) * 64 + lane) * 8];
#pragma unroll
        for (int j = 0; j < 8; ++j) {
            acc[0][j] = __builtin_amdgcn_mfma_f32_16x16x32_bf16(a0, bv[j], acc[0][j], 0, 0, 0);
            acc[1][j] = __builtin_amdgcn_mfma_f32_16x16x32_bf16(a1, bv[j], acc[1][j], 0, 0, 0);
        }
    }

    float b1v[8];
#pragma unroll
    for (int j = 0; j < 8; ++j) b1v[j] = b1[cg * 128 + j * 16 + l15];

#pragma unroll
    for (int i = 0; i < 2; ++i) {
        const int gt = i ? gt1 : gt0;
#pragma unroll
        for (int j = 0; j < 8; ++j)
#pragma unroll
            for (int r = 0; r < 4; ++r)
                sT[wave][(l4 * 4 + r) * 136 + j * 16 + l15] =
                    f2bf(gelu_f(acc[i][j][r] + b1v[j]));
        if (gt < nt16) {
#pragma unroll
            for (int q = 0; q < 4; ++q) {
                float v[8];
#pragma unroll
                for (int e = 0; e < 8; ++e)
                    v[e] = bf2f(sT[wave][l15 * 136 + q * 32 + l4 * 8 + e]) * A1_SCALE;
                unsigned u0 = 0, u1 = 0;
                u0 = __builtin_amdgcn_cvt_pk_fp8_f32(v[0], v[1], u0, false);
                u0 = __builtin_amdgcn_cvt_pk_fp8_f32(v[2], v[3], u0, true);
                u1 = __builtin_amdgcn_cvt_pk_fp8_f32(v[4], v[5], u1, false);
                u1 = __builtin_amdgcn_cvt_pk_fp8_f32(v[6], v[7], u1, true);
                uint2 o; o.x = u0; o.y = u1;
                *(uint2*)(a1img + (((size_t)gt * 16 + cg * 4 + q) * 64 + lane) * 8) = o;
            }
        }
    }
}

// ---------------- FF2: wave-independent fp8 frag GEMM + residual + LN2 -------
__global__ __launch_bounds__(256)
void ff2w_kernel(const unsigned char* __restrict__ a1img,
                 const unsigned char* __restrict__ w2frag8,
                 const ushort_t* __restrict__ hb,
                 const float* __restrict__ b2,
                 const float* __restrict__ g, const float* __restrict__ be,
                 float* __restrict__ out, int M)
{
    const int wave = threadIdx.x >> 6, lane = threadIdx.x & 63;
    const int t32 = blockIdx.x * 4 + wave;
    const int nt32 = (M + 31) / 32;
    if (t32 >= nt32) return;
    const int nt16 = (M + 15) / 16;
    const int gt0 = t32 * 2;
    const int gt1c = (gt0 + 1 < nt16) ? gt0 + 1 : nt16 - 1;
    const int l15 = lane & 15, l4 = lane >> 4;

    floatx4 acc[2][8];
#pragma unroll
    for (int i = 0; i < 2; ++i)
#pragma unroll
        for (int j = 0; j < 8; ++j) acc[i][j] = (floatx4)(0.f);

#pragma unroll
    for (int kst = 0; kst < 16; ++kst) {
        long a0 = *(const long*)(a1img + (((size_t)gt0  * 16 + kst) * 64 + lane) * 8);
        long a1 = *(const long*)(a1img + (((size_t)gt1c * 16 + kst) * 64 + lane) * 8);
        long bv[8];
#pragma unroll
        for (int j = 0; j < 8; ++j)
            bv[j] = *(const long*)(w2frag8 + (((size_t)j * 16 + kst) * 64 + lane) * 8);
#pragma unroll
        for (int j = 0; j < 8; ++j) {
            acc[0][j] = __builtin_amdgcn_mfma_f32_16x16x32_fp8_fp8(a0, bv[j], acc[0][j], 0, 0, 0);
            acc[1][j] = __builtin_amdgcn_mfma_f32_16x16x32_fp8_fp8(a1, bv[j], acc[1][j], 0, 0, 0);
        }
    }

    float b2v[8], gv[8], bev[8];
#pragma unroll
    for (int j = 0; j < 8; ++j) {
        int oc = j * 16 + l15;
        b2v[j] = b2[oc]; gv[j] = g[oc]; bev[j] = be[oc];
    }

#pragma unroll
    for (int i = 0; i < 2; ++i) {
        const int rb = (t32 * 2 + i) * 16;
#pragma unroll
        for (int j = 0; j < 8; ++j) {
            int oc = j * 16 + l15;
#pragma unroll
            for (int r = 0; r < 4; ++r) {
                int row = rb + l4 * 4 + r;
                int rc = (row < M) ? row : M - 1;
                acc[i][j][r] = acc[i][j][r] * FF2_DESCALE + b2v[j]
                             + bf2f(hb[(size_t)rc * HID + oc]);
            }
        }
#pragma unroll
        for (int r = 0; r < 4; ++r) {
            float s1 = 0.f, s2 = 0.f;
#pragma unroll
            for (int j = 0; j < 8; ++j) {
                s1 += acc[i][j][r];
                s2 += acc[i][j][r] * acc[i][j][r];
            }
            s1 += __shfl_xor(s1, 1); s1 += __shfl_xor(s1, 2);
            s1 += __shfl_xor(s1, 4); s1 += __shfl_xor(s1, 8);
            s2 += __shfl_xor(s2, 1); s2 += __shfl_xor(s2, 2);
            s2 += __shfl_xor(s2, 4); s2 += __shfl_xor(s2, 8);
            float mu = s1 * (1.f / 128.f);
            float var = s2 * (1.f / 128.f) - mu * mu;
            float rstd = rsqrtf(var + 1e-5f);
            int row = rb + l4 * 4 + r;
            if (row < M) {
#pragma unroll
                for (int j = 0; j < 8; ++j)
                    out[(size_t)row * HID + j * 16 + l15] =
                        (acc[i][j][r] - mu) * rstd * gv[j] + bev[j];
            }
        }
    }
}

// ---------------- counting-sort scan chain ----------------------------------
__global__ __launch_bounds__(256)
void scan1_kernel(const int* __restrict__ cnt, int* __restrict__ parts, int N)
{
    __shared__ int sd[256];
    int t = threadIdx.x;
    int base = blockIdx.x * 1024 + t * 4;
    int s = 0;
#pragma unroll
    for (int j = 0; j < 4; ++j) if (base + j < N) s += cnt[base + j];
    sd[t] = s; __syncthreads();
    for (int off = 128; off; off >>= 1) {
        if (t < off) sd[t] += sd[t + off];
        __syncthreads();
    }
    if (t == 0) parts[blockIdx.x] = sd[0];
}

__global__ __launch_bounds__(256)
void scan2_kernel(const int* __restrict__ parts, int* __restrict__ poff, int nb)
{
    __shared__ int sd[256];
    int t = threadIdx.x;
    int v = (t < nb) ? parts[t] : 0;
    sd[t] = v; __syncthreads();
    for (int off = 1; off < 256; off <<= 1) {
        int u = (t >= off) ? sd[t - off] : 0;
        __syncthreads();
        sd[t] += u;
        __syncthreads();
    }
    if (t < nb) poff[t] = sd[t] - v;   // exclusive
}

__global__ __launch_bounds__(256)
void scan3_kernel(const int* __restrict__ cnt, const int* __restrict__ poff,
                  int* __restrict__ rp, int N)
{
    __shared__ int sd[256];
    int t = threadIdx.x;
    int base = blockIdx.x * 1024 + t * 4;
    int v0 = (base + 0 < N) ? cnt[base + 0] : 0;
    int v1 = (base + 1 < N) ? cnt[base + 1] : 0;
    int v2 = (base + 2 < N) ? cnt[base + 2] : 0;
    int v3 = (base + 3 < N) ? cnt[base + 3] : 0;
    int s = v0 + v1 + v2 + v3;
    sd[t] = s; __syncthreads();
    for (int off = 1; off < 256; off <<= 1) {
        int u = (t >= off) ? sd[t - off] : 0;
        __syncthreads();
        sd[t] += u;
        __syncthreads();
    }
    int o = poff[blockIdx.x] + sd[t] - s;
    if (base + 0 < N) rp[base + 0] = o;
    if (base + 1 < N) rp[base + 1] = o + v0;
    if (base + 2 < N) rp[base + 2] = o + v0 + v1;
    if (base + 3 < N) rp[base + 3] = o + v0 + v1 + v2;
}

// cohort scatter, ATOMIC-FREE: pos = rp_start[d] + rank[e]. Cohort keyed by
// blockIdx.x & 7 keeps each XCD's writes inside a ~contiguous 1/8 of ssrc
// (the r2-validated write-amp fix); rp is never mutated.
__global__ __launch_bounds__(256)
void scatter_kernel(const int* __restrict__ src, const int* __restrict__ dst,
                    const int* __restrict__ rp, const int* __restrict__ rank,
                    int* __restrict__ ssrc, int E, int N)
{
    int coh = blockIdx.x & 7;
    int bc  = blockIdx.x >> 3;
    int rr  = (N + 7) >> 3;
    int nlo = coh * rr;
    int nhi = nlo + rr; if (nhi > N) nhi = N;
    int stride = (gridDim.x >> 3) * 256;
    for (int e = bc * 256 + threadIdx.x; e < E; e += stride) {
        int d = dst[e];
        if (d >= nlo && d < nhi) ssrc[rp[d] + rank[e]] = src[e];
    }
}

// ---------------- fused attention: 4 edges per wave-step ---------------------
// rp holds exclusive segment STARTS (never mutated): seg n = [rp[n], rp[n+1]),
// rp[N] == E handled via the E param. Output written directly in MFMA
// frag-image layout (consumed by wow).
__global__ __launch_bounds__(256)
void attn_fused_kernel(const ushort_t* __restrict__ qkvb, const int* __restrict__ rp,
                       const int* __restrict__ ssrc, ushort_t* __restrict__ aggfrag,
                       int N, int E)
{
    int wave = threadIdx.x >> 6, lane = threadIdx.x & 63;
    int n = blockIdx.x * 4 + wave;
    if (n >= N) return;
    int grp = lane >> 4;            // 0..3 edge slot
    int cb  = (lane & 15) * 16;     // byte offset of this lane's 16B chunk
    const char* base = (const char*)qkvb;

    short8 qv = *(const short8*)(base + n * QKV_ROWB + cb);
    float q[8];
#pragma unroll
    for (int j = 0; j < 8; ++j) q[j] = bf2f((ushort_t)qv[j]) * (0.25f / KV_SCALE);

    int r0 = rp[n];
    int r1 = (n + 1 < N) ? rp[n + 1] : E;
    float acc[8] = {0.f, 0.f, 0.f, 0.f, 0.f, 0.f, 0.f, 0.f};
    float l = 0.f;

    int r = r0;
    for (; r + 8 <= r1; r += 8) {
        int s0 = ssrc[r + grp];
        int s1 = ssrc[r + 4 + grp];
        uint4 kv0 = *(const uint4*)(base + s0 * QKV_ROWB + 256 + cb);
        uint4 kv1 = *(const uint4*)(base + s1 * QKV_ROWB + 256 + cb);

        f32x2 a0 = __builtin_amdgcn_cvt_pk_f32_fp8(kv0.x, false);
        f32x2 a1 = __builtin_amdgcn_cvt_pk_f32_fp8(kv0.x, true);
        f32x2 a2 = __builtin_amdgcn_cvt_pk_f32_fp8(kv0.y, false);
        f32x2 a3 = __builtin_amdgcn_cvt_pk_f32_fp8(kv0.y, true);
        f32x2 b0 = __builtin_amdgcn_cvt_pk_f32_fp8(kv1.x, false);
        f32x2 b1 = __builtin_amdgcn_cvt_pk_f32_fp8(kv1.x, true);
        f32x2 b2 = __builtin_amdgcn_cvt_pk_f32_fp8(kv1.y, false);
        f32x2 b3 = __builtin_amdgcn_cvt_pk_f32_fp8(kv1.y, true);

        float p0 = 0.f, p1 = 0.f;
        p0 = fmaf(q[0], a0.x, p0); p0 = fmaf(q[1], a0.y, p0);
        p0 = fmaf(q[2], a1.x, p0); p0 = fmaf(q[3], a1.y, p0);
        p0 = fmaf(q[4], a2.x, p0); p0 = fmaf(q[5], a2.y, p0);
        p0 = fmaf(q[6], a3.x, p0); p0 = fmaf(q[7], a3.y, p0);
        p1 = fmaf(q[0], b0.x, p1); p1 = fmaf(q[1], b0.y, p1);
        p1 = fmaf(q[2], b1.x, p1); p1 = fmaf(q[3], b1.y, p1);
        p1 = fmaf(q[4], b2.x, p1); p1 = fmaf(q[5], b2.y, p1);
        p1 = fmaf(q[6], b3.x, p1); p1 = fmaf(q[7], b3.y, p1);

        p0 += __shfl_xor(p0, 1);
        p1 += __shfl_xor(p1, 1);
        float e0 = __expf(p0), e1 = __expf(p1);
        l += e0 + e1;

        f32x2 v0 = __builtin_amdgcn_cvt_pk_f32_fp8(kv0.z, false);
        f32x2 v1 = __builtin_amdgcn_cvt_pk_f32_fp8(kv0.z, true);
        f32x2 v2 = __builtin_amdgcn_cvt_pk_f32_fp8(kv0.w, false);
        f32x2 v3 = __builtin_amdgcn_cvt_pk_f32_fp8(kv0.w, true);
        f32x2 w0 = __builtin_amdgcn_cvt_pk_f32_fp8(kv1.z, false);
        f32x2 w1 = __builtin_amdgcn_cvt_pk_f32_fp8(kv1.z, true);
        f32x2 w2 = __builtin_amdgcn_cvt_pk_f32_fp8(kv1.w, false);
        f32x2 w3 = __builtin_amdgcn_cvt_pk_f32_fp8(kv1.w, true);

        acc[0] = fmaf(e0, v0.x, acc[0]); acc[1] = fmaf(e0, v0.y, acc[1]);
        acc[2] = fmaf(e0, v1.x, acc[2]); acc[3] = fmaf(e0, v1.y, acc[3]);
        acc[4] = fmaf(e0, v2.x, acc[4]); acc[5] = fmaf(e0, v2.y, acc[5]);
        acc[6] = fmaf(e0, v3.x, acc[6]); acc[7] = fmaf(e0, v3.y, acc[7]);
        acc[0] = fmaf(e1, w0.x, acc[0]); acc[1] = fmaf(e1, w0.y, acc[1]);
        acc[2] = fmaf(e1, w1.x, acc[2]); acc[3] = fmaf(e1, w1.y, acc[3]);
        acc[4] = fmaf(e1, w2.x, acc[4]); acc[5] = fmaf(e1, w2.y, acc[5]);
        acc[6] = fmaf(e1, w3.x, acc[6]); acc[7] = fmaf(e1, w3.y, acc[7]);
    }
    for (; r < r1; r += 4) {
        int e = r + grp;
        int s = ssrc[(e < r1) ? e : r0];
        uint4 kv = *(const uint4*)(base + s * QKV_ROWB + 256 + cb);
        f32x2 a0 = __builtin_amdgcn_cvt_pk_f32_fp8(kv.x, false);
        f32x2 a1 = __builtin_amdgcn_cvt_pk_f32_fp8(kv.x, true);
        f32x2 a2 = __builtin_amdgcn_cvt_pk_f32_fp8(kv.y, false);
        f32x2 a3 = __builtin_amdgcn_cvt_pk_f32_fp8(kv.y, true);
        float p = 0.f;
        p = fmaf(q[0], a0.x, p); p = fmaf(q[1], a0.y, p);
        p = fmaf(q[2], a1.x, p); p = fmaf(q[3], a1.y, p);
        p = fmaf(q[4], a2.x, p); p = fmaf(q[5], a2.y, p);
        p = fmaf(q[6], a3.x, p); p = fmaf(q[7], a3.y, p);
        p += __shfl_xor(p, 1);
        float ea = (e < r1) ? __expf(p) : 0.f;
        l += ea;
        f32x2 v0 = __builtin_amdgcn_cvt_pk_f32_fp8(kv.z, false);
        f32x2 v1 = __builtin_amdgcn_cvt_pk_f32_fp8(kv.z, true);
        f32x2 v2 = __builtin_amdgcn_cvt_pk_f32_fp8(kv.w, false);
        f32x2 v3 = __builtin_amdgcn_cvt_pk_f32_fp8(kv.w, true);
        acc[0] = fmaf(ea, v0.x, acc[0]); acc[1] = fmaf(ea, v0.y, acc[1]);
        acc[2] = fmaf(ea, v1.x, acc[2]); acc[3] = fmaf(ea, v1.y, acc[3]);
        acc[4] = fmaf(ea, v2.x, acc[4]); acc[5] = fmaf(ea, v2.y, acc[5]);
        acc[6] = fmaf(ea, v3.x, acc[6]); acc[7] = fmaf(ea, v3.y, acc[7]);
    }

#pragma unroll
    for (int j = 0; j < 8; ++j) {
        acc[j] += __shfl_xor(acc[j], 16);
        acc[j] += __shfl_xor(acc[j], 32);
    }
    l += __shfl_xor(l, 16);
    l += __shfl_xor(l, 32);
    float inv = KV_INV_SCALE / (l + 1e-16f);
    if (grp == 0) {
        short8 o;
#pragma unroll
        for (int j = 0; j < 8; ++j) o[j] = (short)f2bf(acc[j] * inv);
        int t16 = n >> 4, kst = lane >> 2;
        int lp = (n & 15) + ((lane & 3) << 4);
        *(short8*)&aggfrag[(((size_t)t16 * 4 + kst) * 64 + lp) * 8] = o;
    }
}

// ============================================================================
extern "C" void kernel_launch(void* const* d_in, const int* in_sizes, int n_in,
                              void* d_out, int out_size, void* d_ws, size_t ws_size,
                              hipStream_t stream)
{
    const float* x  = (const float*)d_in[0];
    const int*   ei = (const int*)d_in[1];
    const float* Wq = (const float*)d_in[2];
    const float* bq = (const float*)d_in[3];
    const float* Wk = (const float*)d_in[4];
    const float* bk = (const float*)d_in[5];
    const float* Wv = (const float*)d_in[6];
    const float* bv = (const float*)d_in[7];
    const float* Wo = (const float*)d_in[8];
    const float* bo = (const float*)d_in[9];
    const float* W1 = (const float*)d_in[10];
    const float* b1 = (const float*)d_in[11];
    const float* W2 = (const float*)d_in[12];
    const float* b2 = (const float*)d_in[13];
    const float* g1 = (const float*)d_in[14];
    const float* be1= (const float*)d_in[15];
    const float* g2 = (const float*)d_in[16];
    const float* be2= (const float*)d_in[17];
    float* out = (float*)d_out;

    const int N = in_sizes[0] / HID;      // 50000
    const int E = in_sizes[1] / 2;        // 800000
    const int* srcp = ei;
    const int* dstp = ei + E;

    const size_t NH = (size_t)N * HID;    // 6.4M
    float* wsf = (float*)d_ws;

    const int nt16 = (N + 15) / 16;       // 3125
    const int nt32 = (N + 31) / 32;       // 1563

    // ---- workspace layout (f32 units) ----
    ushort_t* xfrag   = (ushort_t*)wsf;                 // [0, 0.5NH)  dies after QKV
    ushort_t* qkvb    = (ushort_t*)(wsf + NH / 2);      // [0.5, 1.5)  dies after attn
    ushort_t* hfrag   = (ushort_t*)(wsf + NH + NH / 2); // [1.5, 2.0)  h frag image
    ushort_t* aggfrag = (ushort_t*)(wsf + 2 * NH);      // [2.0, 2.5)  dies after Wo
    ushort_t* hb      = (ushort_t*)wsf;                 // [0, 0.5)    overlays dead xfrag
    unsigned char* a1img = (unsigned char*)(wsf + NH / 2); // [0.5,1.5) overlays dead qkvb

    ushort_t* U       = (ushort_t*)(wsf + 2 * NH + NH / 2);
    ushort_t* wofrag  = U;                              // 16384 ushort
    ushort_t* wqkvf   = U + 16384;                      // 49152 ushort
    ushort_t* w1frag  = U + 65536;                      // 65536 ushort
    unsigned char* w2frag8 = (unsigned char*)(U + 131072); // 65536 B
    float*    bqkv = (float*)(w2frag8 + 65536);         // 384 f32
    int*      rp   = (int*)(bqkv + 384);                // N+1
    int*      cnt  = rp + (N + 1);                      // N
    int*      poff = cnt + N;                           // 256
    int*      parts= poff + 256;                        // 256
    int*      ssrc = parts + 256;                       // E
    int*      rank = ssrc + E;                          // E

    // ---- prep (streaming only) ----
    hipMemsetAsync(cnt, 0, N * sizeof(int), stream);
    const int xchunks = nt16 * 256;       // 800000
    const int ptot = xchunks + 2048 + 6144 + 8192 + 8192 + 384;
    prep_kernel<<<(ptot + 255) / 256, 256, 0, stream>>>(
        x, Wq, Wk, Wv, Wo, W1, W2, bq, bk, bv,
        xfrag, wofrag, wqkvf, w1frag, w2frag8, bqkv, xchunks);

    // ---- cohort degree count (+per-edge rank) + scans + atomic-free scatter --
    count_kernel<<<2048, 256, 0, stream>>>(dstp, cnt, rank, E, N);
    const int nb = (N + 1023) / 1024;   // 49
    scan1_kernel<<<nb, 256, 0, stream>>>(cnt, parts, N);
    scan2_kernel<<<1, 256, 0, stream>>>(parts, poff, nb);
    scan3_kernel<<<nb, 256, 0, stream>>>(cnt, poff, rp, N);
    scatter_kernel<<<2048, 256, 0, stream>>>(srcp, dstp, rp, rank, ssrc, E, N);

    // ---- QKV (wave-independent frag GEMM): y=0 q bf16, y=1/2 k/v fp8 ----
    qkvw_kernel<<<dim3((nt16 + 7) / 8, 3), 256, 0, stream>>>(
        xfrag, wqkvf, bqkv, qkvb, nt16);

    // ---- fused attention (emits aggfrag in frag-image layout) ----
    attn_fused_kernel<<<(N + 3) / 4, 256, 0, stream>>>(
        qkvb, rp, ssrc, aggfrag, N, E);

    // ---- Wo (wave-independent frag GEMM) + residual(x) + LN1 -> hb + hfrag ----
    wow_kernel<<<(nt32 + 3) / 4, 256, 0, stream>>>(
        aggfrag, wofrag, bo, x, g1, be1, hb, hfrag, N);

    // ---- FF1 (frag images, wave-independent) -> a1 fp8 image ----
    ff1w_kernel<<<nt32, 256, 0, stream>>>(hfrag, w1frag, b1, a1img, N);

    // ---- FF2 (fp8 frag GEMM) + residual(hb) + LN2 -> out (f32) ----
    ff2w_kernel<<<(nt32 + 3) / 4, 256, 0, stream>>>(
        a1img, w2frag8, hb, b2, g2, be2, out, N);
}